// Round 4
// baseline (395.493 us; speedup 1.0000x reference)
//
#include <hip/hip_runtime.h>
#include <math.h>

// IDMPNN fused forward — R4: wave-independent perm chains (R3 math, bit-identical)
// + LDS diet 50KB->32KB (4-5 blocks/CU instead of 2) + final kernel folded into
// main via device-scope atomicMax + counter (last block per graph writes out[b]).
// B=64, NM=32, NS=32, K=3, HID=64, NLAYER=4, P=6. Block=192 thr (3 waves), one
// subgraph; wave w owns perms {2w,2w+1} with a PRIVATE 9216B LDS buffer -> zero
// barriers in the layer loop. GEMM chain oriented producer-M == consumer-K.

#define NBATCH 64
#define NM 32
#define NS 32
#define KSUB 3
#define HID 64
#define NLAYER 4
#define PP 6
#define STOT (NBATCH * NS)

// d_ws layout: ushort-offsets for weight planes, then byte offsets
#define W1H 0
#define W1L 16384
#define W2H 32768
#define W2L 49152
#define S1H 65536
#define S1L 69632            // planes end at ushort 73728 = byte 147456
#define GMAX_BYTE 147456     // uint[64*64]  (16384 B)
#define CNT_BYTE  163840     // uint[64]     (256 B)
#define S2WT_BYTE 164096     // float[64*64] (16384 B)

typedef short bf16x8 __attribute__((ext_vector_type(8)));
typedef float f32x4 __attribute__((ext_vector_type(4)));

#define MFMA(a, b, c) __builtin_amdgcn_mfma_f32_16x16x32_bf16(a, b, c, 0, 0, 0)

__constant__ int c_perm[KSUB][PP] = {
    {0, 0, 1, 1, 2, 2},
    {1, 2, 0, 2, 0, 1},
    {2, 1, 2, 0, 1, 0}
};

union FragU { struct { uint2 a, b; } u; bf16x8 f; };

// interleaved chunk layout: each 4-d chunk = 16B: [0,8)=bf16-hi, [8,16)=bf16-lo
__device__ __forceinline__ bf16x8 frag_rd(const unsigned short* row, int dbase, int off) {
    FragU x;
    x.u.a = *(const uint2*)(row + dbase * 2 + off);
    x.u.b = *(const uint2*)(row + dbase * 2 + 8 + off);
    return x.f;
}

__device__ __forceinline__ void chunk_wr(unsigned short* row, int d0,
                                         float v0, float v1, float v2, float v3) {
    unsigned u0 = __float_as_uint(v0), u1 = __float_as_uint(v1);
    unsigned u2 = __float_as_uint(v2), u3 = __float_as_uint(v3);
    unsigned h0 = __builtin_amdgcn_perm(u1, u0, 0x07060302u);
    unsigned h1 = __builtin_amdgcn_perm(u3, u2, 0x07060302u);
    float r0 = v0 - __uint_as_float(u0 & 0xFFFF0000u);
    float r1 = v1 - __uint_as_float(u1 & 0xFFFF0000u);
    float r2 = v2 - __uint_as_float(u2 & 0xFFFF0000u);
    float r3 = v3 - __uint_as_float(u3 & 0xFFFF0000u);
    unsigned l0 = __builtin_amdgcn_perm(__float_as_uint(r1), __float_as_uint(r0), 0x07060302u);
    unsigned l1 = __builtin_amdgcn_perm(__float_as_uint(r3), __float_as_uint(r2), 0x07060302u);
    *(uint4*)(row + d0 * 2) = make_uint4(h0, h1, l0, l1);
}

__device__ __forceinline__ void pack8(const float* v, bf16x8* hi, bf16x8* lo) {
    unsigned u[8], lu[8];
#pragma unroll
    for (int j = 0; j < 8; ++j) u[j] = __float_as_uint(v[j]);
#pragma unroll
    for (int j = 0; j < 8; ++j)
        lu[j] = __float_as_uint(v[j] - __uint_as_float(u[j] & 0xFFFF0000u));
    FragU H, L;
    H.u.a.x = __builtin_amdgcn_perm(u[1], u[0], 0x07060302u);
    H.u.a.y = __builtin_amdgcn_perm(u[3], u[2], 0x07060302u);
    H.u.b.x = __builtin_amdgcn_perm(u[5], u[4], 0x07060302u);
    H.u.b.y = __builtin_amdgcn_perm(u[7], u[6], 0x07060302u);
    L.u.a.x = __builtin_amdgcn_perm(lu[1], lu[0], 0x07060302u);
    L.u.a.y = __builtin_amdgcn_perm(lu[3], lu[2], 0x07060302u);
    L.u.b.x = __builtin_amdgcn_perm(lu[5], lu[4], 0x07060302u);
    L.u.b.y = __builtin_amdgcn_perm(lu[7], lu[6], 0x07060302u);
    *hi = H.f;
    *lo = L.f;
}

__device__ __forceinline__ unsigned short bf_hi_rne(float x) {
    unsigned u = __float_as_uint(x);
    return (unsigned short)((u + 0x7FFFu + ((u >> 16) & 1u)) >> 16);
}
__device__ __forceinline__ float bf_f(unsigned short h) {
    return __uint_as_float(((unsigned)h) << 16);
}

// ---- prep: weight planes + s2w^T + zero gmax/counters ----
extern "C" __global__ void idmpnn_prep(const float* __restrict__ w1,
                                       const float* __restrict__ w2,
                                       const float* __restrict__ s1w,
                                       const float* __restrict__ s2w,
                                       char* __restrict__ ws)
{
    unsigned short* wsu = (unsigned short*)ws;
    int idx = blockIdx.x * 256 + threadIdx.x;
    float v; int dh, dl;
    if (idx < 16384) {                       // W1^T hi/lo
        int l = idx >> 12, r = idx & 4095, dp = r >> 6, e = r & 63;
        v = w1[l * 4096 + e * 64 + dp];
        dh = W1H + idx; dl = W1L + idx;
    } else if (idx < 32768) {                // W2^T hi/lo
        int k = idx - 16384;
        int l = k >> 12, r = k & 4095, dp = r >> 6, e = r & 63;
        v = w2[l * 4096 + e * 64 + dp];
        dh = W2H + k; dl = W2L + k;
    } else if (idx < 36864) {                // set1_W^T hi/lo
        int k = idx - 32768, dp = k >> 6, e = k & 63;
        v = s1w[e * 64 + dp];
        dh = S1H + k; dl = S1L + k;
    } else if (idx < 40960) {                // set2_W^T f32
        int k = idx - 36864, dp = k >> 6, e = k & 63;
        ((float*)(ws + S2WT_BYTE))[k] = s2w[e * 64 + dp];
        return;
    } else if (idx < 45056) {                // zero gmax
        ((unsigned*)(ws + GMAX_BYTE))[idx - 40960] = 0u;
        return;
    } else if (idx < 45120) {                // zero counters
        ((unsigned*)(ws + CNT_BYTE))[idx - 45056] = 0u;
        return;
    } else return;
    unsigned short hi = bf_hi_rne(v);
    wsu[dh] = hi;
    wsu[dl] = bf_hi_rne(v - bf_f(hi));
}

extern "C" __global__ void __launch_bounds__(192, 3)
idmpnn_main(const int* __restrict__ xg, const float* __restrict__ subadj,
            const int* __restrict__ subgs, const int* __restrict__ num_node,
            const float* __restrict__ idemb, const float* __restrict__ node_emb,
            const float* __restrict__ b1g, const float* __restrict__ b2g,
            const float* __restrict__ lngm, const float* __restrict__ lnbm,
            const float* __restrict__ s1bm, const float* __restrict__ s2bm,
            const float* __restrict__ outw, const float* __restrict__ outb,
            const unsigned short* __restrict__ wsu, const float* __restrict__ s2wt,
            unsigned* __restrict__ gmax, unsigned* __restrict__ cnt,
            float* __restrict__ out)
{
    // 27648 + 768 + 4096 + 256 = 32768 B total LDS
    __shared__ unsigned short WB[3 * 4608];  // per-wave buffer (HB/GB/FB views)
    __shared__ float idS[KSUB * 64];
    __shared__ float prm[NLAYER * 4 * 64];   // b1,b2,g,be per layer
    __shared__ float HSf[HID];

    const int s = blockIdx.x, b = s >> 5;
    const int tid = threadIdx.x;
    const int w = tid / 64, lane = tid & 63;
    const int c = lane & 15, q = lane >> 4;

    // ---- block staging (params only; tiny) ----
    for (int t = tid; t < NLAYER * 4 * 64; t += 192) {
        int l = t >> 8, r2 = t & 255, set = r2 >> 6, d = r2 & 63;
        const float* src = (set == 0) ? b1g : (set == 1) ? b2g : (set == 2) ? lngm : lnbm;
        prm[t] = src[l * HID + d];
    }
    if (tid < KSUB * 64) idS[tid] = idemb[tid];

    const int nd0 = subgs[s * KSUB + 0];
    const int nd1 = subgs[s * KSUB + 1];
    const int nd2 = subgs[s * KSUB + 2];
    const int nn = num_node[b];
    const int zi0 = xg[b * NM + c];
    const int zi1 = xg[b * NM + 16 + c];

    // ---- adjacency B-frags (adjT) in regs: lane holds adj[i=in*16+c][j=8q+jj] ----
    bf16x8 adjh[2], adjl[2];
#pragma unroll
    for (int in_ = 0; in_ < 2; ++in_) {
        const float* ap = subadj + (size_t)b * NM * NM + (in_ * 16 + c) * NM + 8 * q;
        float av[8];
        float4 f0 = *(const float4*)ap;
        float4 f1 = *(const float4*)(ap + 4);
        av[0] = f0.x; av[1] = f0.y; av[2] = f0.z; av[3] = f0.w;
        av[4] = f1.x; av[5] = f1.y; av[6] = f1.z; av[7] = f1.w;
        pack8(av, &adjh[in_], &adjl[in_]);
    }

    __syncthreads();

    unsigned short* wb = WB + w * 4608;   // private buffer
    float accv[32];
#pragma unroll
    for (int e = 0; e < 32; ++e) accv[e] = 0.f;

    for (int pp = 0; pp < 2; ++pp) {
        const int p = w * 2 + pp;

        // ---- h init from global node_emb (L1-hot) ----
        float h[32];
#pragma unroll
        for (int in_ = 0; in_ < 2; ++in_) {
            int i = in_ * 16 + c;
            int z = in_ ? zi1 : zi0;
            int pid = (i == nd0) ? c_perm[0][p] : (i == nd1) ? c_perm[1][p]
                      : (i == nd2) ? c_perm[2][p] : -1;
#pragma unroll
            for (int dm = 0; dm < 4; ++dm) {
                float4 e4 = *(const float4*)(node_emb + (size_t)z * HID + dm * 16 + 4 * q);
                if (pid >= 0) {
                    float4 f4 = *(const float4*)&idS[pid * 64 + dm * 16 + 4 * q];
                    e4.x *= f4.x; e4.y *= f4.y; e4.z *= f4.z; e4.w *= f4.w;
                }
                h[in_ * 16 + dm * 4 + 0] = e4.x;
                h[in_ * 16 + dm * 4 + 1] = e4.y;
                h[in_ * 16 + dm * 4 + 2] = e4.z;
                h[in_ * 16 + dm * 4 + 3] = e4.w;
            }
        }

        for (int l = 0; l < NLAYER; ++l) {
            // (1) h -> HB [i][d]
#pragma unroll
            for (int in_ = 0; in_ < 2; ++in_)
#pragma unroll
                for (int dm = 0; dm < 4; ++dm)
                    chunk_wr(wb + (in_ * 16 + c) * 136, dm * 16 + 4 * q,
                             h[in_ * 16 + dm * 4 + 0], h[in_ * 16 + dm * 4 + 1],
                             h[in_ * 16 + dm * 4 + 2], h[in_ * 16 + dm * 4 + 3]);

            // (2) preload GEMM-A A-frags (before GB overwrites)
            bf16x8 hah[2][2], hal[2][2];
#pragma unroll
            for (int im = 0; im < 2; ++im)
#pragma unroll
                for (int ks = 0; ks < 2; ++ks) {
                    const unsigned short* row = wb + (im * 16 + c) * 136;
                    hah[im][ks] = frag_rd(row, ks * 32 + 8 * q, 0);
                    hal[im][ks] = frag_rd(row, ks * 32 + 8 * q, 4);
                }

            // (3) GEMM-A: g = h @ W1  (m=i, n=d', k=d)
            f32x4 gg[2][4];
#pragma unroll
            for (int im = 0; im < 2; ++im)
#pragma unroll
                for (int jn = 0; jn < 4; ++jn) gg[im][jn] = (f32x4){0.f, 0.f, 0.f, 0.f};
#pragma unroll
            for (int jn = 0; jn < 4; ++jn) {
                const unsigned short* w1h = wsu + W1H + (l * 64 + jn * 16 + c) * 64;
                const unsigned short* w1l = wsu + W1L + (l * 64 + jn * 16 + c) * 64;
#pragma unroll
                for (int ks = 0; ks < 2; ++ks) {
                    bf16x8 bh = *(const bf16x8*)(w1h + ks * 32 + 8 * q);
                    bf16x8 bl = *(const bf16x8*)(w1l + ks * 32 + 8 * q);
#pragma unroll
                    for (int im = 0; im < 2; ++im) {
                        gg[im][jn] = MFMA(hah[im][ks], bh, gg[im][jn]);
                        gg[im][jn] = MFMA(hah[im][ks], bl, gg[im][jn]);
                        gg[im][jn] = MFMA(hal[im][ks], bh, gg[im][jn]);
                    }
                }
            }

            // (4) g -> GB [d'][i]
#pragma unroll
            for (int jn = 0; jn < 4; ++jn)
#pragma unroll
                for (int im = 0; im < 2; ++im)
                    chunk_wr(wb + (jn * 16 + c) * 72, im * 16 + 4 * q,
                             gg[im][jn][0], gg[im][jn][1], gg[im][jn][2], gg[im][jn][3]);

            // (5) preload GEMM-B A-frags (g^T rows, k=j<32)
            bf16x8 gah[4], gal[4];
#pragma unroll
            for (int dm = 0; dm < 4; ++dm) {
                const unsigned short* row = wb + (dm * 16 + c) * 72;
                gah[dm] = frag_rd(row, 8 * q, 0);
                gal[dm] = frag_rd(row, 8 * q, 4);
            }

            // (6) GEMM-B: t^T = g^T @ adjT  (m=d', n=i, k=j)
            f32x4 tt[4][2];
#pragma unroll
            for (int dm = 0; dm < 4; ++dm)
#pragma unroll
                for (int in_ = 0; in_ < 2; ++in_) {
                    f32x4 z = (f32x4){0.f, 0.f, 0.f, 0.f};
                    z = MFMA(gah[dm], adjh[in_], z);
                    z = MFMA(gah[dm], adjl[in_], z);
                    z = MFMA(gal[dm], adjh[in_], z);
                    tt[dm][in_] = z;
                }

            // (7) t -> HB [i][d'] with relu(+b1)
            float4 b1v[4];
#pragma unroll
            for (int dm = 0; dm < 4; ++dm)
                b1v[dm] = *(const float4*)&prm[(l * 4 + 0) * 64 + dm * 16 + 4 * q];
#pragma unroll
            for (int in_ = 0; in_ < 2; ++in_)
#pragma unroll
                for (int dm = 0; dm < 4; ++dm)
                    chunk_wr(wb + (in_ * 16 + c) * 136, dm * 16 + 4 * q,
                             fmaxf(tt[dm][in_][0] + b1v[dm].x, 0.f),
                             fmaxf(tt[dm][in_][1] + b1v[dm].y, 0.f),
                             fmaxf(tt[dm][in_][2] + b1v[dm].z, 0.f),
                             fmaxf(tt[dm][in_][3] + b1v[dm].w, 0.f));

            // (8) preload GEMM-C B-frags (t rows, k=d')
            bf16x8 tbh[2][2], tbl[2][2];
#pragma unroll
            for (int in_ = 0; in_ < 2; ++in_)
#pragma unroll
                for (int ks = 0; ks < 2; ++ks) {
                    const unsigned short* row = wb + (in_ * 16 + c) * 136;
                    tbh[in_][ks] = frag_rd(row, ks * 32 + 8 * q, 0);
                    tbl[in_][ks] = frag_rd(row, ks * 32 + 8 * q, 4);
                }

            // (9) GEMM-C': u^T = W2^T @ t^T  (m=d, n=i, k=d')
            f32x4 uu[4][2];
#pragma unroll
            for (int dm = 0; dm < 4; ++dm)
#pragma unroll
                for (int in_ = 0; in_ < 2; ++in_) uu[dm][in_] = (f32x4){0.f, 0.f, 0.f, 0.f};
#pragma unroll
            for (int dm = 0; dm < 4; ++dm) {
                const unsigned short* w2h = wsu + W2H + (l * 64 + dm * 16 + c) * 64;
                const unsigned short* w2l = wsu + W2L + (l * 64 + dm * 16 + c) * 64;
#pragma unroll
                for (int ks = 0; ks < 2; ++ks) {
                    bf16x8 ah = *(const bf16x8*)(w2h + ks * 32 + 8 * q);
                    bf16x8 al = *(const bf16x8*)(w2l + ks * 32 + 8 * q);
#pragma unroll
                    for (int in_ = 0; in_ < 2; ++in_) {
                        uu[dm][in_] = MFMA(ah, tbh[in_][ks], uu[dm][in_]);
                        uu[dm][in_] = MFMA(ah, tbl[in_][ks], uu[dm][in_]);
                        uu[dm][in_] = MFMA(al, tbh[in_][ks], uu[dm][in_]);
                    }
                }
            }

            // (10) +b2, LayerNorm over d (lane-local 16 + 2 shfls), relu, residual
            float4 b2v[4], gv4[4], bev4[4];
#pragma unroll
            for (int dm = 0; dm < 4; ++dm) {
                b2v[dm]  = *(const float4*)&prm[(l * 4 + 1) * 64 + dm * 16 + 4 * q];
                gv4[dm]  = *(const float4*)&prm[(l * 4 + 2) * 64 + dm * 16 + 4 * q];
                bev4[dm] = *(const float4*)&prm[(l * 4 + 3) * 64 + dm * 16 + 4 * q];
            }
#pragma unroll
            for (int in_ = 0; in_ < 2; ++in_) {
                float v[16];
                float s1 = 0.f, s2 = 0.f;
#pragma unroll
                for (int dm = 0; dm < 4; ++dm) {
                    const float* bb = (const float*)&b2v[dm];
#pragma unroll
                    for (int r = 0; r < 4; ++r) {
                        float x = uu[dm][in_][r] + bb[r];
                        v[dm * 4 + r] = x;
                        s1 += x;
                        s2 += x * x;
                    }
                }
                s1 += __shfl_xor(s1, 16, 64); s1 += __shfl_xor(s1, 32, 64);
                s2 += __shfl_xor(s2, 16, 64); s2 += __shfl_xor(s2, 32, 64);
                float mean = s1 * (1.0f / HID);
                float var  = s2 * (1.0f / HID) - mean * mean;
                float rs   = rsqrtf(var + 1e-5f);
#pragma unroll
                for (int dm = 0; dm < 4; ++dm) {
                    const float* gp = (const float*)&gv4[dm];
                    const float* bp = (const float*)&bev4[dm];
#pragma unroll
                    for (int r = 0; r < 4; ++r) {
                        float y = (v[dm * 4 + r] - mean) * rs * gp[r] + bp[r];
                        h[in_ * 16 + dm * 4 + r] += fmaxf(y, 0.f);
                    }
                }
            }
        }
#pragma unroll
        for (int e = 0; e < 32; ++e) accv[e] += h[e];
    }

    // ---- dump 2-perm sums (f32 [i][d], stride 68) into private buffer ----
    {
        float* FB = (float*)wb;
#pragma unroll
        for (int in_ = 0; in_ < 2; ++in_)
#pragma unroll
            for (int dm = 0; dm < 4; ++dm) {
                float4 o;
                o.x = accv[in_ * 16 + dm * 4 + 0];
                o.y = accv[in_ * 16 + dm * 4 + 1];
                o.z = accv[in_ * 16 + dm * 4 + 2];
                o.w = accv[in_ * 16 + dm * 4 + 3];
                *(float4*)&FB[(in_ * 16 + c) * 68 + dm * 16 + 4 * q] = o;
            }
    }
    __syncthreads();

    // ---- tail (wave 0 only): combine perms, GEMM-D, colsum, set2, pooling ----
    if (w == 0) {
        const float* F0 = (const float*)(WB + 0 * 4608);
        const float* F1 = (const float*)(WB + 1 * 4608);
        const float* F2 = (const float*)(WB + 2 * 4608);

        // build hm A-frags in-register from the three f32 dumps
        bf16x8 mah[2][2], mal[2][2];
#pragma unroll
        for (int im = 0; im < 2; ++im) {
            int i = im * 16 + c;
            float sc = (i < nn) ? (1.0f / PP) : 0.f;
#pragma unroll
            for (int ks = 0; ks < 2; ++ks) {
                int base = i * 68 + ks * 32 + 8 * q;
                float4 a0 = *(const float4*)&F0[base], a1 = *(const float4*)&F0[base + 4];
                float4 b0 = *(const float4*)&F1[base], b1 = *(const float4*)&F1[base + 4];
                float4 c0 = *(const float4*)&F2[base], c1 = *(const float4*)&F2[base + 4];
                float sv[8];
                sv[0] = (a0.x + b0.x + c0.x) * sc; sv[1] = (a0.y + b0.y + c0.y) * sc;
                sv[2] = (a0.z + b0.z + c0.z) * sc; sv[3] = (a0.w + b0.w + c0.w) * sc;
                sv[4] = (a1.x + b1.x + c1.x) * sc; sv[5] = (a1.y + b1.y + c1.y) * sc;
                sv[6] = (a1.z + b1.z + c1.z) * sc; sv[7] = (a1.w + b1.w + c1.w) * sc;
                pack8(sv, &mah[im][ks], &mal[im][ks]);
            }
        }

        // GEMM-D: h1 = hm @ set1_W  (m=i, n=dout)
        f32x4 hh[2][4];
#pragma unroll
        for (int im = 0; im < 2; ++im)
#pragma unroll
            for (int jn = 0; jn < 4; ++jn) hh[im][jn] = (f32x4){0.f, 0.f, 0.f, 0.f};
#pragma unroll
        for (int jn = 0; jn < 4; ++jn) {
            const unsigned short* s1h = wsu + S1H + (jn * 16 + c) * 64;
            const unsigned short* s1l = wsu + S1L + (jn * 16 + c) * 64;
#pragma unroll
            for (int ks = 0; ks < 2; ++ks) {
                bf16x8 bh = *(const bf16x8*)(s1h + ks * 32 + 8 * q);
                bf16x8 bl = *(const bf16x8*)(s1l + ks * 32 + 8 * q);
#pragma unroll
                for (int im = 0; im < 2; ++im) {
                    hh[im][jn] = MFMA(mah[im][ks], bh, hh[im][jn]);
                    hh[im][jn] = MFMA(mah[im][ks], bl, hh[im][jn]);
                    hh[im][jn] = MFMA(mal[im][ks], bh, hh[im][jn]);
                }
            }
        }
        // colsum over all 32 rows (padded rows contribute relu(s1b), as reference)
#pragma unroll
        for (int jn = 0; jn < 4; ++jn) {
            float sb = s1bm[jn * 16 + c];
            float cs = 0.f;
#pragma unroll
            for (int im = 0; im < 2; ++im)
#pragma unroll
                for (int r = 0; r < 4; ++r)
                    cs += fmaxf(hh[im][jn][r] + sb, 0.f);
            cs += __shfl_xor(cs, 16, 64);
            cs += __shfl_xor(cs, 32, 64);
            if (q == 0) HSf[jn * 16 + c] = cs;
        }

        // h2 = relu(HS @ set2_W + s2b), lane = dout (contiguous s2wT rows)
        float acc = 0.f;
#pragma unroll
        for (int e4 = 0; e4 < 16; ++e4) {
            float4 wv = *(const float4*)&s2wt[lane * 64 + e4 * 4];
            float4 hv = *(const float4*)&HSf[e4 * 4];
            acc += hv.x * wv.x + hv.y * wv.y + hv.z * wv.z + hv.w * wv.w;
        }
        float h2 = fmaxf(acc + s2bm[lane], 0.f);

        // pooling fold: device-scope atomicMax (h2 >= 0 so uint order == float order)
        atomicMax(&gmax[b * HID + lane], __float_as_uint(h2));
        __threadfence();
        unsigned old = 0;
        if (lane == 0) old = atomicAdd(&cnt[b], 1u);
        old = __shfl(old, 0, 64);
        if (old == NS - 1) {   // last block of this graph
            __threadfence();
            unsigned mbits = atomicOr(&gmax[b * HID + lane], 0u);  // coherent read
            float v = __uint_as_float(mbits) * outw[lane];
#pragma unroll
            for (int off = 32; off > 0; off >>= 1) v += __shfl_xor(v, off, 64);
            if (lane == 0) out[b] = v + outb[0];
        }
    }
}

extern "C" void kernel_launch(void* const* d_in, const int* in_sizes, int n_in,
                              void* d_out, int out_size, void* d_ws, size_t ws_size,
                              hipStream_t stream)
{
    const int*   xg       = (const int*)d_in[0];
    const float* subadj   = (const float*)d_in[1];
    const int*   subgs    = (const int*)d_in[2];
    const int*   num_node = (const int*)d_in[3];
    const float* idemb    = (const float*)d_in[5];
    const float* node_emb = (const float*)d_in[6];
    const float* w1       = (const float*)d_in[7];
    const float* b1       = (const float*)d_in[8];
    const float* w2       = (const float*)d_in[9];
    const float* b2       = (const float*)d_in[10];
    const float* g        = (const float*)d_in[11];
    const float* be       = (const float*)d_in[12];
    const float* s1w      = (const float*)d_in[13];
    const float* s1b      = (const float*)d_in[14];
    const float* s2w      = (const float*)d_in[15];
    const float* s2b      = (const float*)d_in[16];
    const float* outw     = (const float*)d_in[17];
    const float* outb     = (const float*)d_in[18];

    char* ws = (char*)d_ws;
    unsigned short* wsu = (unsigned short*)ws;
    const float* s2wt = (const float*)(ws + S2WT_BYTE);
    unsigned* gmax = (unsigned*)(ws + GMAX_BYTE);
    unsigned* cnt  = (unsigned*)(ws + CNT_BYTE);

    idmpnn_prep<<<192, 256, 0, stream>>>(w1, w2, s1w, s2w, ws);
    idmpnn_main<<<STOT, 192, 0, stream>>>(xg, subadj, subgs, num_node, idemb, node_emb,
                                          b1, b2, g, be, s1b, s2b, outw, outb,
                                          wsu, s2wt, gmax, cnt, (float*)d_out);
}

// Round 5
// 317.099 us; speedup vs baseline: 1.2472x; 1.2472x over previous
//
#include <hip/hip_runtime.h>
#include <math.h>

// IDMPNN fused forward — R5: R4 structure (32KB LDS, fused final via atomics)
// with __launch_bounds__(192,2) restored. R4's (192,3) made the allocator
// squeeze to 84 VGPRs -> scratch spill (149MB WRITE_SIZE/dispatch!) -> 350us.
// R3 compiled this math at 124 VGPRs under (192,2): 512/124 = 4 waves/SIMD,
// 32KB LDS * 4 = 128KB <= 160KB, so 4 blocks/CU happen naturally, no forcing.
// B=64, NM=32, NS=32, K=3, HID=64, NLAYER=4, P=6. Block=192 thr (3 waves), one
// subgraph; wave w owns perms {2w,2w+1} with a PRIVATE 9216B LDS buffer -> zero
// barriers in the layer loop. GEMM chain oriented producer-M == consumer-K.

#define NBATCH 64
#define NM 32
#define NS 32
#define KSUB 3
#define HID 64
#define NLAYER 4
#define PP 6
#define STOT (NBATCH * NS)

// d_ws layout: ushort-offsets for weight planes, then byte offsets
#define W1H 0
#define W1L 16384
#define W2H 32768
#define W2L 49152
#define S1H 65536
#define S1L 69632            // planes end at ushort 73728 = byte 147456
#define GMAX_BYTE 147456     // uint[64*64]  (16384 B)
#define CNT_BYTE  163840     // uint[64]     (256 B)
#define S2WT_BYTE 164096     // float[64*64] (16384 B)

typedef short bf16x8 __attribute__((ext_vector_type(8)));
typedef float f32x4 __attribute__((ext_vector_type(4)));

#define MFMA(a, b, c) __builtin_amdgcn_mfma_f32_16x16x32_bf16(a, b, c, 0, 0, 0)

__constant__ int c_perm[KSUB][PP] = {
    {0, 0, 1, 1, 2, 2},
    {1, 2, 0, 2, 0, 1},
    {2, 1, 2, 0, 1, 0}
};

union FragU { struct { uint2 a, b; } u; bf16x8 f; };

// interleaved chunk layout: each 4-d chunk = 16B: [0,8)=bf16-hi, [8,16)=bf16-lo
__device__ __forceinline__ bf16x8 frag_rd(const unsigned short* row, int dbase, int off) {
    FragU x;
    x.u.a = *(const uint2*)(row + dbase * 2 + off);
    x.u.b = *(const uint2*)(row + dbase * 2 + 8 + off);
    return x.f;
}

__device__ __forceinline__ void chunk_wr(unsigned short* row, int d0,
                                         float v0, float v1, float v2, float v3) {
    unsigned u0 = __float_as_uint(v0), u1 = __float_as_uint(v1);
    unsigned u2 = __float_as_uint(v2), u3 = __float_as_uint(v3);
    unsigned h0 = __builtin_amdgcn_perm(u1, u0, 0x07060302u);
    unsigned h1 = __builtin_amdgcn_perm(u3, u2, 0x07060302u);
    float r0 = v0 - __uint_as_float(u0 & 0xFFFF0000u);
    float r1 = v1 - __uint_as_float(u1 & 0xFFFF0000u);
    float r2 = v2 - __uint_as_float(u2 & 0xFFFF0000u);
    float r3 = v3 - __uint_as_float(u3 & 0xFFFF0000u);
    unsigned l0 = __builtin_amdgcn_perm(__float_as_uint(r1), __float_as_uint(r0), 0x07060302u);
    unsigned l1 = __builtin_amdgcn_perm(__float_as_uint(r3), __float_as_uint(r2), 0x07060302u);
    *(uint4*)(row + d0 * 2) = make_uint4(h0, h1, l0, l1);
}

__device__ __forceinline__ void pack8(const float* v, bf16x8* hi, bf16x8* lo) {
    unsigned u[8], lu[8];
#pragma unroll
    for (int j = 0; j < 8; ++j) u[j] = __float_as_uint(v[j]);
#pragma unroll
    for (int j = 0; j < 8; ++j)
        lu[j] = __float_as_uint(v[j] - __uint_as_float(u[j] & 0xFFFF0000u));
    FragU H, L;
    H.u.a.x = __builtin_amdgcn_perm(u[1], u[0], 0x07060302u);
    H.u.a.y = __builtin_amdgcn_perm(u[3], u[2], 0x07060302u);
    H.u.b.x = __builtin_amdgcn_perm(u[5], u[4], 0x07060302u);
    H.u.b.y = __builtin_amdgcn_perm(u[7], u[6], 0x07060302u);
    L.u.a.x = __builtin_amdgcn_perm(lu[1], lu[0], 0x07060302u);
    L.u.a.y = __builtin_amdgcn_perm(lu[3], lu[2], 0x07060302u);
    L.u.b.x = __builtin_amdgcn_perm(lu[5], lu[4], 0x07060302u);
    L.u.b.y = __builtin_amdgcn_perm(lu[7], lu[6], 0x07060302u);
    *hi = H.f;
    *lo = L.f;
}

__device__ __forceinline__ unsigned short bf_hi_rne(float x) {
    unsigned u = __float_as_uint(x);
    return (unsigned short)((u + 0x7FFFu + ((u >> 16) & 1u)) >> 16);
}
__device__ __forceinline__ float bf_f(unsigned short h) {
    return __uint_as_float(((unsigned)h) << 16);
}

// ---- prep: weight planes + s2w^T + zero gmax/counters ----
extern "C" __global__ void idmpnn_prep(const float* __restrict__ w1,
                                       const float* __restrict__ w2,
                                       const float* __restrict__ s1w,
                                       const float* __restrict__ s2w,
                                       char* __restrict__ ws)
{
    unsigned short* wsu = (unsigned short*)ws;
    int idx = blockIdx.x * 256 + threadIdx.x;
    float v; int dh, dl;
    if (idx < 16384) {                       // W1^T hi/lo
        int l = idx >> 12, r = idx & 4095, dp = r >> 6, e = r & 63;
        v = w1[l * 4096 + e * 64 + dp];
        dh = W1H + idx; dl = W1L + idx;
    } else if (idx < 32768) {                // W2^T hi/lo
        int k = idx - 16384;
        int l = k >> 12, r = k & 4095, dp = r >> 6, e = r & 63;
        v = w2[l * 4096 + e * 64 + dp];
        dh = W2H + k; dl = W2L + k;
    } else if (idx < 36864) {                // set1_W^T hi/lo
        int k = idx - 32768, dp = k >> 6, e = k & 63;
        v = s1w[e * 64 + dp];
        dh = S1H + k; dl = S1L + k;
    } else if (idx < 40960) {                // set2_W^T f32
        int k = idx - 36864, dp = k >> 6, e = k & 63;
        ((float*)(ws + S2WT_BYTE))[k] = s2w[e * 64 + dp];
        return;
    } else if (idx < 45056) {                // zero gmax
        ((unsigned*)(ws + GMAX_BYTE))[idx - 40960] = 0u;
        return;
    } else if (idx < 45120) {                // zero counters
        ((unsigned*)(ws + CNT_BYTE))[idx - 45056] = 0u;
        return;
    } else return;
    unsigned short hi = bf_hi_rne(v);
    wsu[dh] = hi;
    wsu[dl] = bf_hi_rne(v - bf_f(hi));
}

extern "C" __global__ void __launch_bounds__(192, 2)
idmpnn_main(const int* __restrict__ xg, const float* __restrict__ subadj,
            const int* __restrict__ subgs, const int* __restrict__ num_node,
            const float* __restrict__ idemb, const float* __restrict__ node_emb,
            const float* __restrict__ b1g, const float* __restrict__ b2g,
            const float* __restrict__ lngm, const float* __restrict__ lnbm,
            const float* __restrict__ s1bm, const float* __restrict__ s2bm,
            const float* __restrict__ outw, const float* __restrict__ outb,
            const unsigned short* __restrict__ wsu, const float* __restrict__ s2wt,
            unsigned* __restrict__ gmax, unsigned* __restrict__ cnt,
            float* __restrict__ out)
{
    // 27648 + 768 + 4096 + 256 = 32768 B total LDS
    __shared__ unsigned short WB[3 * 4608];  // per-wave buffer (HB/GB/FB views)
    __shared__ float idS[KSUB * 64];
    __shared__ float prm[NLAYER * 4 * 64];   // b1,b2,g,be per layer
    __shared__ float HSf[HID];

    const int s = blockIdx.x, b = s >> 5;
    const int tid = threadIdx.x;
    const int w = tid / 64, lane = tid & 63;
    const int c = lane & 15, q = lane >> 4;

    // ---- block staging (params only; tiny) ----
    for (int t = tid; t < NLAYER * 4 * 64; t += 192) {
        int l = t >> 8, r2 = t & 255, set = r2 >> 6, d = r2 & 63;
        const float* src = (set == 0) ? b1g : (set == 1) ? b2g : (set == 2) ? lngm : lnbm;
        prm[t] = src[l * HID + d];
    }
    if (tid < KSUB * 64) idS[tid] = idemb[tid];

    const int nd0 = subgs[s * KSUB + 0];
    const int nd1 = subgs[s * KSUB + 1];
    const int nd2 = subgs[s * KSUB + 2];
    const int nn = num_node[b];
    const int zi0 = xg[b * NM + c];
    const int zi1 = xg[b * NM + 16 + c];

    // ---- adjacency B-frags (adjT) in regs: lane holds adj[i=in*16+c][j=8q+jj] ----
    bf16x8 adjh[2], adjl[2];
#pragma unroll
    for (int in_ = 0; in_ < 2; ++in_) {
        const float* ap = subadj + (size_t)b * NM * NM + (in_ * 16 + c) * NM + 8 * q;
        float av[8];
        float4 f0 = *(const float4*)ap;
        float4 f1 = *(const float4*)(ap + 4);
        av[0] = f0.x; av[1] = f0.y; av[2] = f0.z; av[3] = f0.w;
        av[4] = f1.x; av[5] = f1.y; av[6] = f1.z; av[7] = f1.w;
        pack8(av, &adjh[in_], &adjl[in_]);
    }

    __syncthreads();

    unsigned short* wb = WB + w * 4608;   // private buffer
    float accv[32];
#pragma unroll
    for (int e = 0; e < 32; ++e) accv[e] = 0.f;

    for (int pp = 0; pp < 2; ++pp) {
        const int p = w * 2 + pp;

        // ---- h init from global node_emb (L1-hot) ----
        float h[32];
#pragma unroll
        for (int in_ = 0; in_ < 2; ++in_) {
            int i = in_ * 16 + c;
            int z = in_ ? zi1 : zi0;
            int pid = (i == nd0) ? c_perm[0][p] : (i == nd1) ? c_perm[1][p]
                      : (i == nd2) ? c_perm[2][p] : -1;
#pragma unroll
            for (int dm = 0; dm < 4; ++dm) {
                float4 e4 = *(const float4*)(node_emb + (size_t)z * HID + dm * 16 + 4 * q);
                if (pid >= 0) {
                    float4 f4 = *(const float4*)&idS[pid * 64 + dm * 16 + 4 * q];
                    e4.x *= f4.x; e4.y *= f4.y; e4.z *= f4.z; e4.w *= f4.w;
                }
                h[in_ * 16 + dm * 4 + 0] = e4.x;
                h[in_ * 16 + dm * 4 + 1] = e4.y;
                h[in_ * 16 + dm * 4 + 2] = e4.z;
                h[in_ * 16 + dm * 4 + 3] = e4.w;
            }
        }

        for (int l = 0; l < NLAYER; ++l) {
            // (1) h -> HB [i][d]
#pragma unroll
            for (int in_ = 0; in_ < 2; ++in_)
#pragma unroll
                for (int dm = 0; dm < 4; ++dm)
                    chunk_wr(wb + (in_ * 16 + c) * 136, dm * 16 + 4 * q,
                             h[in_ * 16 + dm * 4 + 0], h[in_ * 16 + dm * 4 + 1],
                             h[in_ * 16 + dm * 4 + 2], h[in_ * 16 + dm * 4 + 3]);

            // (2) preload GEMM-A A-frags (before GB overwrites)
            bf16x8 hah[2][2], hal[2][2];
#pragma unroll
            for (int im = 0; im < 2; ++im)
#pragma unroll
                for (int ks = 0; ks < 2; ++ks) {
                    const unsigned short* row = wb + (im * 16 + c) * 136;
                    hah[im][ks] = frag_rd(row, ks * 32 + 8 * q, 0);
                    hal[im][ks] = frag_rd(row, ks * 32 + 8 * q, 4);
                }

            // (3) GEMM-A: g = h @ W1  (m=i, n=d', k=d)
            f32x4 gg[2][4];
#pragma unroll
            for (int im = 0; im < 2; ++im)
#pragma unroll
                for (int jn = 0; jn < 4; ++jn) gg[im][jn] = (f32x4){0.f, 0.f, 0.f, 0.f};
#pragma unroll
            for (int jn = 0; jn < 4; ++jn) {
                const unsigned short* w1h = wsu + W1H + (l * 64 + jn * 16 + c) * 64;
                const unsigned short* w1l = wsu + W1L + (l * 64 + jn * 16 + c) * 64;
#pragma unroll
                for (int ks = 0; ks < 2; ++ks) {
                    bf16x8 bh = *(const bf16x8*)(w1h + ks * 32 + 8 * q);
                    bf16x8 bl = *(const bf16x8*)(w1l + ks * 32 + 8 * q);
#pragma unroll
                    for (int im = 0; im < 2; ++im) {
                        gg[im][jn] = MFMA(hah[im][ks], bh, gg[im][jn]);
                        gg[im][jn] = MFMA(hah[im][ks], bl, gg[im][jn]);
                        gg[im][jn] = MFMA(hal[im][ks], bh, gg[im][jn]);
                    }
                }
            }

            // (4) g -> GB [d'][i]
#pragma unroll
            for (int jn = 0; jn < 4; ++jn)
#pragma unroll
                for (int im = 0; im < 2; ++im)
                    chunk_wr(wb + (jn * 16 + c) * 72, im * 16 + 4 * q,
                             gg[im][jn][0], gg[im][jn][1], gg[im][jn][2], gg[im][jn][3]);

            // (5) preload GEMM-B A-frags (g^T rows, k=j<32)
            bf16x8 gah[4], gal[4];
#pragma unroll
            for (int dm = 0; dm < 4; ++dm) {
                const unsigned short* row = wb + (dm * 16 + c) * 72;
                gah[dm] = frag_rd(row, 8 * q, 0);
                gal[dm] = frag_rd(row, 8 * q, 4);
            }

            // (6) GEMM-B: t^T = g^T @ adjT  (m=d', n=i, k=j)
            f32x4 tt[4][2];
#pragma unroll
            for (int dm = 0; dm < 4; ++dm)
#pragma unroll
                for (int in_ = 0; in_ < 2; ++in_) {
                    f32x4 z = (f32x4){0.f, 0.f, 0.f, 0.f};
                    z = MFMA(gah[dm], adjh[in_], z);
                    z = MFMA(gah[dm], adjl[in_], z);
                    z = MFMA(gal[dm], adjh[in_], z);
                    tt[dm][in_] = z;
                }

            // (7) t -> HB [i][d'] with relu(+b1)
            float4 b1v[4];
#pragma unroll
            for (int dm = 0; dm < 4; ++dm)
                b1v[dm] = *(const float4*)&prm[(l * 4 + 0) * 64 + dm * 16 + 4 * q];
#pragma unroll
            for (int in_ = 0; in_ < 2; ++in_)
#pragma unroll
                for (int dm = 0; dm < 4; ++dm)
                    chunk_wr(wb + (in_ * 16 + c) * 136, dm * 16 + 4 * q,
                             fmaxf(tt[dm][in_][0] + b1v[dm].x, 0.f),
                             fmaxf(tt[dm][in_][1] + b1v[dm].y, 0.f),
                             fmaxf(tt[dm][in_][2] + b1v[dm].z, 0.f),
                             fmaxf(tt[dm][in_][3] + b1v[dm].w, 0.f));

            // (8) preload GEMM-C B-frags (t rows, k=d')
            bf16x8 tbh[2][2], tbl[2][2];
#pragma unroll
            for (int in_ = 0; in_ < 2; ++in_)
#pragma unroll
                for (int ks = 0; ks < 2; ++ks) {
                    const unsigned short* row = wb + (in_ * 16 + c) * 136;
                    tbh[in_][ks] = frag_rd(row, ks * 32 + 8 * q, 0);
                    tbl[in_][ks] = frag_rd(row, ks * 32 + 8 * q, 4);
                }

            // (9) GEMM-C': u^T = W2^T @ t^T  (m=d, n=i, k=d')
            f32x4 uu[4][2];
#pragma unroll
            for (int dm = 0; dm < 4; ++dm)
#pragma unroll
                for (int in_ = 0; in_ < 2; ++in_) uu[dm][in_] = (f32x4){0.f, 0.f, 0.f, 0.f};
#pragma unroll
            for (int dm = 0; dm < 4; ++dm) {
                const unsigned short* w2h = wsu + W2H + (l * 64 + dm * 16 + c) * 64;
                const unsigned short* w2l = wsu + W2L + (l * 64 + dm * 16 + c) * 64;
#pragma unroll
                for (int ks = 0; ks < 2; ++ks) {
                    bf16x8 ah = *(const bf16x8*)(w2h + ks * 32 + 8 * q);
                    bf16x8 al = *(const bf16x8*)(w2l + ks * 32 + 8 * q);
#pragma unroll
                    for (int in_ = 0; in_ < 2; ++in_) {
                        uu[dm][in_] = MFMA(ah, tbh[in_][ks], uu[dm][in_]);
                        uu[dm][in_] = MFMA(ah, tbl[in_][ks], uu[dm][in_]);
                        uu[dm][in_] = MFMA(al, tbh[in_][ks], uu[dm][in_]);
                    }
                }
            }

            // (10) +b2, LayerNorm over d (lane-local 16 + 2 shfls), relu, residual
            float4 b2v[4], gv4[4], bev4[4];
#pragma unroll
            for (int dm = 0; dm < 4; ++dm) {
                b2v[dm]  = *(const float4*)&prm[(l * 4 + 1) * 64 + dm * 16 + 4 * q];
                gv4[dm]  = *(const float4*)&prm[(l * 4 + 2) * 64 + dm * 16 + 4 * q];
                bev4[dm] = *(const float4*)&prm[(l * 4 + 3) * 64 + dm * 16 + 4 * q];
            }
#pragma unroll
            for (int in_ = 0; in_ < 2; ++in_) {
                float v[16];
                float s1 = 0.f, s2 = 0.f;
#pragma unroll
                for (int dm = 0; dm < 4; ++dm) {
                    const float* bb = (const float*)&b2v[dm];
#pragma unroll
                    for (int r = 0; r < 4; ++r) {
                        float x = uu[dm][in_][r] + bb[r];
                        v[dm * 4 + r] = x;
                        s1 += x;
                        s2 += x * x;
                    }
                }
                s1 += __shfl_xor(s1, 16, 64); s1 += __shfl_xor(s1, 32, 64);
                s2 += __shfl_xor(s2, 16, 64); s2 += __shfl_xor(s2, 32, 64);
                float mean = s1 * (1.0f / HID);
                float var  = s2 * (1.0f / HID) - mean * mean;
                float rs   = rsqrtf(var + 1e-5f);
#pragma unroll
                for (int dm = 0; dm < 4; ++dm) {
                    const float* gp = (const float*)&gv4[dm];
                    const float* bp = (const float*)&bev4[dm];
#pragma unroll
                    for (int r = 0; r < 4; ++r) {
                        float y = (v[dm * 4 + r] - mean) * rs * gp[r] + bp[r];
                        h[in_ * 16 + dm * 4 + r] += fmaxf(y, 0.f);
                    }
                }
            }
        }
#pragma unroll
        for (int e = 0; e < 32; ++e) accv[e] += h[e];
    }

    // ---- dump 2-perm sums (f32 [i][d], stride 68) into private buffer ----
    {
        float* FB = (float*)wb;
#pragma unroll
        for (int in_ = 0; in_ < 2; ++in_)
#pragma unroll
            for (int dm = 0; dm < 4; ++dm) {
                float4 o;
                o.x = accv[in_ * 16 + dm * 4 + 0];
                o.y = accv[in_ * 16 + dm * 4 + 1];
                o.z = accv[in_ * 16 + dm * 4 + 2];
                o.w = accv[in_ * 16 + dm * 4 + 3];
                *(float4*)&FB[(in_ * 16 + c) * 68 + dm * 16 + 4 * q] = o;
            }
    }
    __syncthreads();

    // ---- tail (wave 0 only): combine perms, GEMM-D, colsum, set2, pooling ----
    if (w == 0) {
        const float* F0 = (const float*)(WB + 0 * 4608);
        const float* F1 = (const float*)(WB + 1 * 4608);
        const float* F2 = (const float*)(WB + 2 * 4608);

        // build hm A-frags in-register from the three f32 dumps
        bf16x8 mah[2][2], mal[2][2];
#pragma unroll
        for (int im = 0; im < 2; ++im) {
            int i = im * 16 + c;
            float sc = (i < nn) ? (1.0f / PP) : 0.f;
#pragma unroll
            for (int ks = 0; ks < 2; ++ks) {
                int base = i * 68 + ks * 32 + 8 * q;
                float4 a0 = *(const float4*)&F0[base], a1 = *(const float4*)&F0[base + 4];
                float4 b0 = *(const float4*)&F1[base], b1 = *(const float4*)&F1[base + 4];
                float4 c0 = *(const float4*)&F2[base], c1 = *(const float4*)&F2[base + 4];
                float sv[8];
                sv[0] = (a0.x + b0.x + c0.x) * sc; sv[1] = (a0.y + b0.y + c0.y) * sc;
                sv[2] = (a0.z + b0.z + c0.z) * sc; sv[3] = (a0.w + b0.w + c0.w) * sc;
                sv[4] = (a1.x + b1.x + c1.x) * sc; sv[5] = (a1.y + b1.y + c1.y) * sc;
                sv[6] = (a1.z + b1.z + c1.z) * sc; sv[7] = (a1.w + b1.w + c1.w) * sc;
                pack8(sv, &mah[im][ks], &mal[im][ks]);
            }
        }

        // GEMM-D: h1 = hm @ set1_W  (m=i, n=dout)
        f32x4 hh[2][4];
#pragma unroll
        for (int im = 0; im < 2; ++im)
#pragma unroll
            for (int jn = 0; jn < 4; ++jn) hh[im][jn] = (f32x4){0.f, 0.f, 0.f, 0.f};
#pragma unroll
        for (int jn = 0; jn < 4; ++jn) {
            const unsigned short* s1h = wsu + S1H + (jn * 16 + c) * 64;
            const unsigned short* s1l = wsu + S1L + (jn * 16 + c) * 64;
#pragma unroll
            for (int ks = 0; ks < 2; ++ks) {
                bf16x8 bh = *(const bf16x8*)(s1h + ks * 32 + 8 * q);
                bf16x8 bl = *(const bf16x8*)(s1l + ks * 32 + 8 * q);
#pragma unroll
                for (int im = 0; im < 2; ++im) {
                    hh[im][jn] = MFMA(mah[im][ks], bh, hh[im][jn]);
                    hh[im][jn] = MFMA(mah[im][ks], bl, hh[im][jn]);
                    hh[im][jn] = MFMA(mal[im][ks], bh, hh[im][jn]);
                }
            }
        }
        // colsum over all 32 rows (padded rows contribute relu(s1b), as reference)
#pragma unroll
        for (int jn = 0; jn < 4; ++jn) {
            float sb = s1bm[jn * 16 + c];
            float cs = 0.f;
#pragma unroll
            for (int im = 0; im < 2; ++im)
#pragma unroll
                for (int r = 0; r < 4; ++r)
                    cs += fmaxf(hh[im][jn][r] + sb, 0.f);
            cs += __shfl_xor(cs, 16, 64);
            cs += __shfl_xor(cs, 32, 64);
            if (q == 0) HSf[jn * 16 + c] = cs;
        }

        // h2 = relu(HS @ set2_W + s2b), lane = dout (contiguous s2wT rows)
        float acc = 0.f;
#pragma unroll
        for (int e4 = 0; e4 < 16; ++e4) {
            float4 wv = *(const float4*)&s2wt[lane * 64 + e4 * 4];
            float4 hv = *(const float4*)&HSf[e4 * 4];
            acc += hv.x * wv.x + hv.y * wv.y + hv.z * wv.z + hv.w * wv.w;
        }
        float h2 = fmaxf(acc + s2bm[lane], 0.f);

        // pooling fold: device-scope atomicMax (h2 >= 0 so uint order == float order)
        atomicMax(&gmax[b * HID + lane], __float_as_uint(h2));
        __threadfence();
        unsigned old = 0;
        if (lane == 0) old = atomicAdd(&cnt[b], 1u);
        old = __shfl(old, 0, 64);
        if (old == NS - 1) {   // last block of this graph
            __threadfence();
            unsigned mbits = atomicOr(&gmax[b * HID + lane], 0u);  // coherent read
            float v = __uint_as_float(mbits) * outw[lane];
#pragma unroll
            for (int off = 32; off > 0; off >>= 1) v += __shfl_xor(v, off, 64);
            if (lane == 0) out[b] = v + outb[0];
        }
    }
}

extern "C" void kernel_launch(void* const* d_in, const int* in_sizes, int n_in,
                              void* d_out, int out_size, void* d_ws, size_t ws_size,
                              hipStream_t stream)
{
    const int*   xg       = (const int*)d_in[0];
    const float* subadj   = (const float*)d_in[1];
    const int*   subgs    = (const int*)d_in[2];
    const int*   num_node = (const int*)d_in[3];
    const float* idemb    = (const float*)d_in[5];
    const float* node_emb = (const float*)d_in[6];
    const float* w1       = (const float*)d_in[7];
    const float* b1       = (const float*)d_in[8];
    const float* w2       = (const float*)d_in[9];
    const float* b2       = (const float*)d_in[10];
    const float* g        = (const float*)d_in[11];
    const float* be       = (const float*)d_in[12];
    const float* s1w      = (const float*)d_in[13];
    const float* s1b      = (const float*)d_in[14];
    const float* s2w      = (const float*)d_in[15];
    const float* s2b      = (const float*)d_in[16];
    const float* outw     = (const float*)d_in[17];
    const float* outb     = (const float*)d_in[18];

    char* ws = (char*)d_ws;
    unsigned short* wsu = (unsigned short*)ws;
    const float* s2wt = (const float*)(ws + S2WT_BYTE);
    unsigned* gmax = (unsigned*)(ws + GMAX_BYTE);
    unsigned* cnt  = (unsigned*)(ws + CNT_BYTE);

    idmpnn_prep<<<192, 256, 0, stream>>>(w1, w2, s1w, s2w, ws);
    idmpnn_main<<<STOT, 192, 0, stream>>>(xg, subadj, subgs, num_node, idemb, node_emb,
                                          b1, b2, g, be, s1b, s2b, outw, outb,
                                          wsu, s2wt, gmax, cnt, (float*)d_out);
}

// Round 6
// 298.275 us; speedup vs baseline: 1.3259x; 1.0631x over previous
//
#include <hip/hip_runtime.h>
#include <math.h>

// IDMPNN fused forward — R6: fp16 single-term MFMA (was bf16 hi/lo 3-term).
// fp16 RNE: 2.4e-4 rel/rounding, ~13 GEMMs -> ~1e-3 rel final, threshold is 2e-2 rel.
// Cuts: MFMA/layer 120->40, LDS bytes /2, lo-fragments gone, acc live <=16
// -> total regs ~155, __launch_bounds__(192,3) caps at 170 => 3 waves/SIMD,
// 12 waves/CU, 4 blocks/CU (R3/R5 were stuck at 2 blocks: 124 arch + ~128 acc
// VGPRs = 256 total = 2 waves/SIMD). Structure otherwise = R5 (verified):
// block = subgraph, 3 waves, wave w owns perms {2w,2w+1}, private LDS buffer,
// zero barriers in layer loop, fused tail with device atomics.

#define NBATCH 64
#define NM 32
#define NS 32
#define KSUB 3
#define HID 64
#define NLAYER 4
#define PP 6
#define STOT (NBATCH * NS)

// d_ws: fp16 weight planes (ushort offsets), then byte offsets
#define W1F 0            // [l][dout][din] 16384
#define W2F 16384
#define S1F 32768        // planes end at ushort 36864 = byte 73728
#define GMAX_BYTE 73728  // uint[64*64]
#define CNT_BYTE  90112  // uint[64]
#define S2WT_BYTE 90368  // float[64*64]

// LDS row strides (ushorts)
#define SH 68    // HB/FB rows (32 x 64 fp16 + pad)
#define SG 36    // GB rows (64 x 32 fp16 + pad)
#define WBU 2304 // per-wave buffer ushorts (4608B): max(32*68, 64*36)

typedef _Float16 f16x8 __attribute__((ext_vector_type(8)));
typedef float f32x4 __attribute__((ext_vector_type(4)));

#define MFMA16(a, b, c) __builtin_amdgcn_mfma_f32_16x16x32_f16(a, b, c, 0, 0, 0)

__constant__ int c_perm[KSUB][PP] = {
    {0, 0, 1, 1, 2, 2},
    {1, 2, 0, 2, 0, 1},
    {2, 1, 2, 0, 1, 0}
};

__device__ __forceinline__ uint2 pk4(float a, float b, float c, float d) {
    union { _Float16 h[4]; uint2 u; } x;
    x.h[0] = (_Float16)a; x.h[1] = (_Float16)b;
    x.h[2] = (_Float16)c; x.h[3] = (_Float16)d;
    return x.u;
}
__device__ __forceinline__ f16x8 frd(const unsigned short* p) {   // LDS, 8B-aligned
    union { struct { uint2 a, b; } u; f16x8 f; } x;
    x.u.a = *(const uint2*)p;
    x.u.b = *(const uint2*)(p + 4);
    return x.f;
}
__device__ __forceinline__ f16x8 gfrd(const unsigned short* p) {  // global, 16B-aligned
    union { uint4 u; f16x8 f; } x;
    x.u = *(const uint4*)p;
    return x.f;
}

// ---- prep: fp16 weight planes [l][dout][din] + s2w^T f32 + zero gmax/cnt ----
extern "C" __global__ void idmpnn_prep(const float* __restrict__ w1,
                                       const float* __restrict__ w2,
                                       const float* __restrict__ s1w,
                                       const float* __restrict__ s2w,
                                       char* __restrict__ ws)
{
    unsigned short* wsu = (unsigned short*)ws;
    int idx = blockIdx.x * 256 + threadIdx.x;
    float v; int dst;
    if (idx < 16384) {
        int l = idx >> 12, r = idx & 4095, dp = r >> 6, e = r & 63;
        v = w1[l * 4096 + e * 64 + dp];
        dst = W1F + idx;
    } else if (idx < 32768) {
        int k = idx - 16384;
        int l = k >> 12, r = k & 4095, dp = r >> 6, e = r & 63;
        v = w2[l * 4096 + e * 64 + dp];
        dst = W2F + k;
    } else if (idx < 36864) {
        int k = idx - 32768, dp = k >> 6, e = k & 63;
        v = s1w[e * 64 + dp];
        dst = S1F + k;
    } else if (idx < 40960) {
        int k = idx - 36864, dp = k >> 6, e = k & 63;
        ((float*)(ws + S2WT_BYTE))[k] = s2w[e * 64 + dp];
        return;
    } else if (idx < 45056) {
        ((unsigned*)(ws + GMAX_BYTE))[idx - 40960] = 0u;
        return;
    } else if (idx < 45120) {
        ((unsigned*)(ws + CNT_BYTE))[idx - 45056] = 0u;
        return;
    } else return;
    union { _Float16 h; unsigned short u; } cv;
    cv.h = (_Float16)v;                 // RNE
    wsu[dst] = cv.u;
}

extern "C" __global__ void __launch_bounds__(192, 3)
idmpnn_main(const int* __restrict__ xg, const float* __restrict__ subadj,
            const int* __restrict__ subgs, const int* __restrict__ num_node,
            const float* __restrict__ idemb, const float* __restrict__ node_emb,
            const float* __restrict__ b1g, const float* __restrict__ b2g,
            const float* __restrict__ lngm, const float* __restrict__ lnbm,
            const float* __restrict__ s1bm, const float* __restrict__ s2bm,
            const float* __restrict__ outw, const float* __restrict__ outb,
            const unsigned short* __restrict__ wsf, const float* __restrict__ s2wt,
            unsigned* __restrict__ gmax, unsigned* __restrict__ cnt,
            float* __restrict__ out)
{
    // 13824 + 768 + 4096 + 256 = 18944 B LDS
    __shared__ unsigned short WB[3 * WBU];   // per-wave HB/GB/FB views
    __shared__ float idS[KSUB * 64];
    __shared__ float prm[NLAYER * 4 * 64];   // b1,b2,g,be per layer
    __shared__ float HSf[HID];

    const int s = blockIdx.x, b = s >> 5;
    const int tid = threadIdx.x;
    const int w = tid / 64, lane = tid & 63;
    const int c = lane & 15, q = lane >> 4;

    for (int t = tid; t < NLAYER * 4 * 64; t += 192) {
        int l = t >> 8, r2 = t & 255, set = r2 >> 6, d = r2 & 63;
        const float* src = (set == 0) ? b1g : (set == 1) ? b2g : (set == 2) ? lngm : lnbm;
        prm[t] = src[l * HID + d];
    }
    if (tid < KSUB * 64) idS[tid] = idemb[tid];

    const int nd0 = subgs[s * KSUB + 0];
    const int nd1 = subgs[s * KSUB + 1];
    const int nd2 = subgs[s * KSUB + 2];
    const int nn = num_node[b];
    const int zi0 = xg[b * NM + c];
    const int zi1 = xg[b * NM + 16 + c];

    // adjacency fp16 B-frags: lane holds adj[i=in*16+c][j=8q+jj], regs
    f16x8 adjf[2];
#pragma unroll
    for (int in_ = 0; in_ < 2; ++in_) {
        const float* ap = subadj + (size_t)b * NM * NM + (in_ * 16 + c) * NM + 8 * q;
        float4 f0 = *(const float4*)ap;
        float4 f1 = *(const float4*)(ap + 4);
        f16x8 r;
        r[0] = (_Float16)f0.x; r[1] = (_Float16)f0.y;
        r[2] = (_Float16)f0.z; r[3] = (_Float16)f0.w;
        r[4] = (_Float16)f1.x; r[5] = (_Float16)f1.y;
        r[6] = (_Float16)f1.z; r[7] = (_Float16)f1.w;
        adjf[in_] = r;
    }

    __syncthreads();

    unsigned short* wb = WB + w * WBU;
    float accv[32];
#pragma unroll
    for (int e = 0; e < 32; ++e) accv[e] = 0.f;

#pragma unroll 1
    for (int pp = 0; pp < 2; ++pp) {
        const int p = w * 2 + pp;

        // h init: h[in*16+dm*4+r] = value at (i=in*16+c, d=dm*16+4q+r), fp32
        float h[32];
#pragma unroll
        for (int in_ = 0; in_ < 2; ++in_) {
            int i = in_ * 16 + c;
            int z = in_ ? zi1 : zi0;
            int pid = (i == nd0) ? c_perm[0][p] : (i == nd1) ? c_perm[1][p]
                      : (i == nd2) ? c_perm[2][p] : -1;
#pragma unroll
            for (int dm = 0; dm < 4; ++dm) {
                float4 e4 = *(const float4*)(node_emb + (size_t)z * HID + dm * 16 + 4 * q);
                if (pid >= 0) {
                    float4 f4 = *(const float4*)&idS[pid * 64 + dm * 16 + 4 * q];
                    e4.x *= f4.x; e4.y *= f4.y; e4.z *= f4.z; e4.w *= f4.w;
                }
                h[in_ * 16 + dm * 4 + 0] = e4.x;
                h[in_ * 16 + dm * 4 + 1] = e4.y;
                h[in_ * 16 + dm * 4 + 2] = e4.z;
                h[in_ * 16 + dm * 4 + 3] = e4.w;
            }
        }

#pragma unroll 1
        for (int l = 0; l < NLAYER; ++l) {
            // (1) h -> HB [i][d]
#pragma unroll
            for (int in_ = 0; in_ < 2; ++in_)
#pragma unroll
                for (int dm = 0; dm < 4; ++dm)
                    *(uint2*)(wb + (in_ * 16 + c) * SH + dm * 16 + 4 * q) =
                        pk4(h[in_ * 16 + dm * 4 + 0], h[in_ * 16 + dm * 4 + 1],
                            h[in_ * 16 + dm * 4 + 2], h[in_ * 16 + dm * 4 + 3]);

            // (2) preload GEMM-A A-frags (all, before GB overwrites)
            f16x8 hah[2][2];
#pragma unroll
            for (int im = 0; im < 2; ++im)
#pragma unroll
                for (int ks = 0; ks < 2; ++ks)
                    hah[im][ks] = frd(wb + (im * 16 + c) * SH + ks * 32 + 8 * q);

            // (3+4) GEMM-A: g = h @ W1 (m=i,n=d',k=d); write GB [d'][i] per jn
#pragma unroll
            for (int jn = 0; jn < 4; ++jn) {
                const unsigned short* wp = wsf + W1F + (l * 64 + jn * 16 + c) * 64;
                f16x8 b0 = gfrd(wp + 8 * q);
                f16x8 b1 = gfrd(wp + 32 + 8 * q);
                f32x4 g0 = {0.f, 0.f, 0.f, 0.f}, g1 = {0.f, 0.f, 0.f, 0.f};
                g0 = MFMA16(hah[0][0], b0, g0);
                g0 = MFMA16(hah[0][1], b1, g0);
                g1 = MFMA16(hah[1][0], b0, g1);
                g1 = MFMA16(hah[1][1], b1, g1);
                *(uint2*)(wb + (jn * 16 + c) * SG + 4 * q)      = pk4(g0[0], g0[1], g0[2], g0[3]);
                *(uint2*)(wb + (jn * 16 + c) * SG + 16 + 4 * q) = pk4(g1[0], g1[1], g1[2], g1[3]);
            }

            // (5) preload GEMM-B A-frags (g^T rows)
            f16x8 gah[4];
#pragma unroll
            for (int dm = 0; dm < 4; ++dm)
                gah[dm] = frd(wb + (dm * 16 + c) * SG + 8 * q);

            // (6+7) GEMM-B: t^T = g^T @ adjT (m=d',n=i,k=j); t -> HB with relu(+b1)
            float4 b1v[4];
#pragma unroll
            for (int dm = 0; dm < 4; ++dm)
                b1v[dm] = *(const float4*)&prm[(l * 4 + 0) * 64 + dm * 16 + 4 * q];
#pragma unroll
            for (int dm = 0; dm < 4; ++dm) {
                f32x4 t0 = {0.f, 0.f, 0.f, 0.f}, t1 = {0.f, 0.f, 0.f, 0.f};
                t0 = MFMA16(gah[dm], adjf[0], t0);
                t1 = MFMA16(gah[dm], adjf[1], t1);
                *(uint2*)(wb + c * SH + dm * 16 + 4 * q) =
                    pk4(fmaxf(t0[0] + b1v[dm].x, 0.f), fmaxf(t0[1] + b1v[dm].y, 0.f),
                        fmaxf(t0[2] + b1v[dm].z, 0.f), fmaxf(t0[3] + b1v[dm].w, 0.f));
                *(uint2*)(wb + (16 + c) * SH + dm * 16 + 4 * q) =
                    pk4(fmaxf(t1[0] + b1v[dm].x, 0.f), fmaxf(t1[1] + b1v[dm].y, 0.f),
                        fmaxf(t1[2] + b1v[dm].z, 0.f), fmaxf(t1[3] + b1v[dm].w, 0.f));
            }

            // (8) preload GEMM-C B-frags (t rows)
            f16x8 tbh[2][2];
#pragma unroll
            for (int in_ = 0; in_ < 2; ++in_)
#pragma unroll
                for (int ks = 0; ks < 2; ++ks)
                    tbh[in_][ks] = frd(wb + (in_ * 16 + c) * SH + ks * 32 + 8 * q);

            // (9+10) GEMM-C': u^T = W2^T @ t^T (m=d,n=i,k=d'); LN; relu; residual
            float4 b2v[4], gv4[4], bev4[4];
#pragma unroll
            for (int dm = 0; dm < 4; ++dm) {
                b2v[dm]  = *(const float4*)&prm[(l * 4 + 1) * 64 + dm * 16 + 4 * q];
                gv4[dm]  = *(const float4*)&prm[(l * 4 + 2) * 64 + dm * 16 + 4 * q];
                bev4[dm] = *(const float4*)&prm[(l * 4 + 3) * 64 + dm * 16 + 4 * q];
            }
#pragma unroll
            for (int in_ = 0; in_ < 2; ++in_) {
                float v[16];
                float s1 = 0.f, s2 = 0.f;
#pragma unroll
                for (int dm = 0; dm < 4; ++dm) {
                    const unsigned short* wp2 = wsf + W2F + (l * 64 + dm * 16 + c) * 64;
                    f16x8 a0 = gfrd(wp2 + 8 * q);
                    f16x8 a1 = gfrd(wp2 + 32 + 8 * q);
                    f32x4 u = {0.f, 0.f, 0.f, 0.f};
                    u = MFMA16(a0, tbh[in_][0], u);
                    u = MFMA16(a1, tbh[in_][1], u);
                    const float* bb = (const float*)&b2v[dm];
#pragma unroll
                    for (int r = 0; r < 4; ++r) {
                        float x = u[r] + bb[r];
                        v[dm * 4 + r] = x;
                        s1 += x;
                        s2 += x * x;
                    }
                }
                s1 += __shfl_xor(s1, 16, 64); s1 += __shfl_xor(s1, 32, 64);
                s2 += __shfl_xor(s2, 16, 64); s2 += __shfl_xor(s2, 32, 64);
                float mean = s1 * (1.0f / HID);
                float var  = s2 * (1.0f / HID) - mean * mean;
                float rs   = rsqrtf(var + 1e-5f);
#pragma unroll
                for (int dm = 0; dm < 4; ++dm) {
                    const float* gp = (const float*)&gv4[dm];
                    const float* bp = (const float*)&bev4[dm];
#pragma unroll
                    for (int r = 0; r < 4; ++r) {
                        float y = (v[dm * 4 + r] - mean) * rs * gp[r] + bp[r];
                        h[in_ * 16 + dm * 4 + r] += fmaxf(y, 0.f);
                    }
                }
            }
        }
#pragma unroll
        for (int e = 0; e < 32; ++e) accv[e] += h[e];
    }

    // ---- dump 2-perm sums as fp16 [i][d] into private buffer ----
#pragma unroll
    for (int in_ = 0; in_ < 2; ++in_)
#pragma unroll
        for (int dm = 0; dm < 4; ++dm)
            *(uint2*)(wb + (in_ * 16 + c) * SH + dm * 16 + 4 * q) =
                pk4(accv[in_ * 16 + dm * 4 + 0], accv[in_ * 16 + dm * 4 + 1],
                    accv[in_ * 16 + dm * 4 + 2], accv[in_ * 16 + dm * 4 + 3]);
    __syncthreads();

    // ---- tail (wave 0): combine perms, GEMM-D, colsum, set2, pooling ----
    if (w == 0) {
        f16x8 mah[2][2];
#pragma unroll
        for (int im = 0; im < 2; ++im) {
            float sc = ((im * 16 + c) < nn) ? (1.0f / PP) : 0.f;
#pragma unroll
            for (int ks = 0; ks < 2; ++ks) {
                int ro = (im * 16 + c) * SH + ks * 32 + 8 * q;
                f16x8 fa = frd(WB + 0 * WBU + ro);
                f16x8 fb = frd(WB + 1 * WBU + ro);
                f16x8 fc = frd(WB + 2 * WBU + ro);
                f16x8 m;
#pragma unroll
                for (int j = 0; j < 8; ++j)
                    m[j] = (_Float16)(((float)fa[j] + (float)fb[j] + (float)fc[j]) * sc);
                mah[im][ks] = m;
            }
        }

        // GEMM-D: h1 = hm @ set1_W (m=i, n=dout)
        f32x4 hh[2][4];
#pragma unroll
        for (int im = 0; im < 2; ++im)
#pragma unroll
            for (int jn = 0; jn < 4; ++jn) hh[im][jn] = (f32x4){0.f, 0.f, 0.f, 0.f};
#pragma unroll
        for (int jn = 0; jn < 4; ++jn) {
            const unsigned short* sp = wsf + S1F + (jn * 16 + c) * 64;
            f16x8 b0 = gfrd(sp + 8 * q);
            f16x8 b1 = gfrd(sp + 32 + 8 * q);
#pragma unroll
            for (int im = 0; im < 2; ++im) {
                hh[im][jn] = MFMA16(mah[im][0], b0, hh[im][jn]);
                hh[im][jn] = MFMA16(mah[im][1], b1, hh[im][jn]);
            }
        }
        // colsum over all 32 rows (padded rows contribute relu(s1b), as ref)
#pragma unroll
        for (int jn = 0; jn < 4; ++jn) {
            float sb = s1bm[jn * 16 + c];
            float cs = 0.f;
#pragma unroll
            for (int im = 0; im < 2; ++im)
#pragma unroll
                for (int r = 0; r < 4; ++r)
                    cs += fmaxf(hh[im][jn][r] + sb, 0.f);
            cs += __shfl_xor(cs, 16, 64);
            cs += __shfl_xor(cs, 32, 64);
            if (q == 0) HSf[jn * 16 + c] = cs;
        }

        // h2 = relu(HS @ set2_W + s2b), lane = dout
        float acc = 0.f;
#pragma unroll
        for (int e4 = 0; e4 < 16; ++e4) {
            float4 wv = *(const float4*)&s2wt[lane * 64 + e4 * 4];
            float4 hv = *(const float4*)&HSf[e4 * 4];
            acc += hv.x * wv.x + hv.y * wv.y + hv.z * wv.z + hv.w * wv.w;
        }
        float h2 = fmaxf(acc + s2bm[lane], 0.f);

        // pooling fold: device-scope atomicMax (h2 >= 0: uint order == float order)
        atomicMax(&gmax[b * HID + lane], __float_as_uint(h2));
        __threadfence();
        unsigned old = 0;
        if (lane == 0) old = atomicAdd(&cnt[b], 1u);
        old = __shfl(old, 0, 64);
        if (old == NS - 1) {   // last block of this graph
            __threadfence();
            unsigned mbits = atomicOr(&gmax[b * HID + lane], 0u);
            float v = __uint_as_float(mbits) * outw[lane];
#pragma unroll
            for (int off = 32; off > 0; off >>= 1) v += __shfl_xor(v, off, 64);
            if (lane == 0) out[b] = v + outb[0];
        }
    }
}

extern "C" void kernel_launch(void* const* d_in, const int* in_sizes, int n_in,
                              void* d_out, int out_size, void* d_ws, size_t ws_size,
                              hipStream_t stream)
{
    const int*   xg       = (const int*)d_in[0];
    const float* subadj   = (const float*)d_in[1];
    const int*   subgs    = (const int*)d_in[2];
    const int*   num_node = (const int*)d_in[3];
    const float* idemb    = (const float*)d_in[5];
    const float* node_emb = (const float*)d_in[6];
    const float* w1       = (const float*)d_in[7];
    const float* b1       = (const float*)d_in[8];
    const float* w2       = (const float*)d_in[9];
    const float* b2       = (const float*)d_in[10];
    const float* g        = (const float*)d_in[11];
    const float* be       = (const float*)d_in[12];
    const float* s1w      = (const float*)d_in[13];
    const float* s1b      = (const float*)d_in[14];
    const float* s2w      = (const float*)d_in[15];
    const float* s2b      = (const float*)d_in[16];
    const float* outw     = (const float*)d_in[17];
    const float* outb     = (const float*)d_in[18];

    char* ws = (char*)d_ws;
    unsigned short* wsf = (unsigned short*)ws;
    const float* s2wt = (const float*)(ws + S2WT_BYTE);
    unsigned* gmax = (unsigned*)(ws + GMAX_BYTE);
    unsigned* cnt  = (unsigned*)(ws + CNT_BYTE);

    idmpnn_prep<<<177, 256, 0, stream>>>(w1, w2, s1w, s2w, ws);
    idmpnn_main<<<STOT, 192, 0, stream>>>(xg, subadj, subgs, num_node, idemb, node_emb,
                                          b1, b2, g, be, s1b, s2b, outw, outb,
                                          wsf, s2wt, gmax, cnt, (float*)d_out);
}

// Round 7
// 249.852 us; speedup vs baseline: 1.5829x; 1.1938x over previous
//
#include <hip/hip_runtime.h>
#include <math.h>

// IDMPNN fused forward — R7: fp16 MFMA, ONE PERM PER WAVE, packed-fp16 residual.
// R6 post-mortem: (192,3) => unified-RF split 84 arch + 84 acc; fp32 h[32]+accv[32]
// didn't fit 84 arch => 131MB/dispatch scratch spill. Fix: kill accv (1 perm/wave,
// block = 384thr = 6 waves) and pack h as 2xfp16 in 16 VGPRs (the GEMM path already
// quantizes h to fp16 at every LDS write). Persistent state ~35 regs < 84.
// Block = subgraph; wave w owns perm w with a private 4608B LDS buffer; zero
// barriers in the layer loop; fused tail (wave 0) + device-atomic segment-max.

#define NBATCH 64
#define NM 32
#define NS 32
#define KSUB 3
#define HID 64
#define NLAYER 4
#define PP 6
#define STOT (NBATCH * NS)

// d_ws: fp16 weight planes (ushort offsets), then byte offsets
#define W1F 0            // [l][dout][din] 16384
#define W2F 16384
#define S1F 32768        // planes end at ushort 36864 = byte 73728
#define GMAX_BYTE 73728  // uint[64*64]
#define CNT_BYTE  90112  // uint[64]
#define S2WT_BYTE 90368  // float[64*64]

// LDS row strides (ushorts)
#define SH 68    // HB rows (32 x 64 fp16 + pad)
#define SG 36    // GB rows (64 x 32 fp16 + pad)
#define WBU 2304 // per-wave buffer ushorts (4608B): max(32*68, 64*36)

typedef _Float16 f16x8 __attribute__((ext_vector_type(8)));
typedef float f32x4 __attribute__((ext_vector_type(4)));

#define MFMA16(a, b, c) __builtin_amdgcn_mfma_f32_16x16x32_f16(a, b, c, 0, 0, 0)

__constant__ int c_perm[KSUB][PP] = {
    {0, 0, 1, 1, 2, 2},
    {1, 2, 0, 2, 0, 1},
    {2, 1, 2, 0, 1, 0}
};

__device__ __forceinline__ uint2 pk4(float a, float b, float c, float d) {
    union { _Float16 h[4]; uint2 u; } x;
    x.h[0] = (_Float16)a; x.h[1] = (_Float16)b;
    x.h[2] = (_Float16)c; x.h[3] = (_Float16)d;
    return x.u;
}
__device__ __forceinline__ float2 upk2(unsigned u) {
    union { unsigned u; _Float16 h[2]; } x; x.u = u;
    return make_float2((float)x.h[0], (float)x.h[1]);
}
__device__ __forceinline__ f16x8 frd(const unsigned short* p) {   // LDS, 8B-aligned
    union { struct { uint2 a, b; } u; f16x8 f; } x;
    x.u.a = *(const uint2*)p;
    x.u.b = *(const uint2*)(p + 4);
    return x.f;
}
__device__ __forceinline__ f16x8 gfrd(const unsigned short* p) {  // global, 16B-aligned
    union { uint4 u; f16x8 f; } x;
    x.u = *(const uint4*)p;
    return x.f;
}

// ---- prep: fp16 weight planes [l][dout][din] + s2w^T f32 + zero gmax/cnt ----
extern "C" __global__ void idmpnn_prep(const float* __restrict__ w1,
                                       const float* __restrict__ w2,
                                       const float* __restrict__ s1w,
                                       const float* __restrict__ s2w,
                                       char* __restrict__ ws)
{
    unsigned short* wsu = (unsigned short*)ws;
    int idx = blockIdx.x * 256 + threadIdx.x;
    float v; int dst;
    if (idx < 16384) {
        int l = idx >> 12, r = idx & 4095, dp = r >> 6, e = r & 63;
        v = w1[l * 4096 + e * 64 + dp];
        dst = W1F + idx;
    } else if (idx < 32768) {
        int k = idx - 16384;
        int l = k >> 12, r = k & 4095, dp = r >> 6, e = r & 63;
        v = w2[l * 4096 + e * 64 + dp];
        dst = W2F + k;
    } else if (idx < 36864) {
        int k = idx - 32768, dp = k >> 6, e = k & 63;
        v = s1w[e * 64 + dp];
        dst = S1F + k;
    } else if (idx < 40960) {
        int k = idx - 36864, dp = k >> 6, e = k & 63;
        ((float*)(ws + S2WT_BYTE))[k] = s2w[e * 64 + dp];
        return;
    } else if (idx < 45056) {
        ((unsigned*)(ws + GMAX_BYTE))[idx - 40960] = 0u;
        return;
    } else if (idx < 45120) {
        ((unsigned*)(ws + CNT_BYTE))[idx - 45056] = 0u;
        return;
    } else return;
    union { _Float16 h; unsigned short u; } cv;
    cv.h = (_Float16)v;                 // RNE
    wsu[dst] = cv.u;
}

extern "C" __global__ void __launch_bounds__(384, 3)
idmpnn_main(const int* __restrict__ xg, const float* __restrict__ subadj,
            const int* __restrict__ subgs, const int* __restrict__ num_node,
            const float* __restrict__ idemb, const float* __restrict__ node_emb,
            const float* __restrict__ b1g, const float* __restrict__ b2g,
            const float* __restrict__ lngm, const float* __restrict__ lnbm,
            const float* __restrict__ s1bm, const float* __restrict__ s2bm,
            const float* __restrict__ outw, const float* __restrict__ outb,
            const unsigned short* __restrict__ wsf, const float* __restrict__ s2wt,
            unsigned* __restrict__ gmax, unsigned* __restrict__ cnt,
            float* __restrict__ out)
{
    // 27648 + 768 + 4096 + 256 = 32768 B LDS
    __shared__ unsigned short WB[6 * WBU];   // per-wave HB/GB views + final dump
    __shared__ float idS[KSUB * 64];
    __shared__ float prm[NLAYER * 4 * 64];   // b1,b2,g,be per layer
    __shared__ float HSf[HID];

    const int s = blockIdx.x, b = s >> 5;
    const int tid = threadIdx.x;
    const int w = tid / 64, lane = tid & 63;  // w = perm id, 0..5
    const int c = lane & 15, q = lane >> 4;

    for (int t = tid; t < NLAYER * 4 * 64; t += 384) {
        int l = t >> 8, r2 = t & 255, set = r2 >> 6, d = r2 & 63;
        const float* src = (set == 0) ? b1g : (set == 1) ? b2g : (set == 2) ? lngm : lnbm;
        prm[t] = src[l * HID + d];
    }
    if (tid < KSUB * 64) idS[tid] = idemb[tid];

    const int nd0 = subgs[s * KSUB + 0];
    const int nd1 = subgs[s * KSUB + 1];
    const int nd2 = subgs[s * KSUB + 2];
    const int nn = num_node[b];
    const int zi0 = xg[b * NM + c];
    const int zi1 = xg[b * NM + 16 + c];

    // adjacency fp16 B-frags: lane holds adj[i=in*16+c][j=8q+jj], regs
    f16x8 adjf[2];
#pragma unroll
    for (int in_ = 0; in_ < 2; ++in_) {
        const float* ap = subadj + (size_t)b * NM * NM + (in_ * 16 + c) * NM + 8 * q;
        float4 f0 = *(const float4*)ap;
        float4 f1 = *(const float4*)(ap + 4);
        f16x8 r;
        r[0] = (_Float16)f0.x; r[1] = (_Float16)f0.y;
        r[2] = (_Float16)f0.z; r[3] = (_Float16)f0.w;
        r[4] = (_Float16)f1.x; r[5] = (_Float16)f1.y;
        r[6] = (_Float16)f1.z; r[7] = (_Float16)f1.w;
        adjf[in_] = r;
    }

    __syncthreads();

    unsigned short* wb = WB + w * WBU;
    const int p = w;   // this wave's permutation

    // ---- h init, packed 2xfp16: hpk[in_*8 + dm*2 + g2] holds d = dm*16+4q+2*g2+{0,1}
    unsigned hpk[16];
#pragma unroll
    for (int in_ = 0; in_ < 2; ++in_) {
        int i = in_ * 16 + c;
        int z = in_ ? zi1 : zi0;
        int pid = (i == nd0) ? c_perm[0][p] : (i == nd1) ? c_perm[1][p]
                  : (i == nd2) ? c_perm[2][p] : -1;
#pragma unroll
        for (int dm = 0; dm < 4; ++dm) {
            float4 e4 = *(const float4*)(node_emb + (size_t)z * HID + dm * 16 + 4 * q);
            if (pid >= 0) {
                float4 f4 = *(const float4*)&idS[pid * 64 + dm * 16 + 4 * q];
                e4.x *= f4.x; e4.y *= f4.y; e4.z *= f4.z; e4.w *= f4.w;
            }
            uint2 u = pk4(e4.x, e4.y, e4.z, e4.w);
            hpk[in_ * 8 + dm * 2 + 0] = u.x;
            hpk[in_ * 8 + dm * 2 + 1] = u.y;
        }
    }

#pragma unroll 1
    for (int l = 0; l < NLAYER; ++l) {
        // (1) h -> HB [i][d]  (hpk is already the LDS layout: pure reg moves)
#pragma unroll
        for (int in_ = 0; in_ < 2; ++in_)
#pragma unroll
            for (int dm = 0; dm < 4; ++dm)
                *(uint2*)(wb + (in_ * 16 + c) * SH + dm * 16 + 4 * q) =
                    make_uint2(hpk[in_ * 8 + dm * 2], hpk[in_ * 8 + dm * 2 + 1]);

        // (2) preload GEMM-A A-frags (all, before GB overwrites)
        f16x8 hah[2][2];
#pragma unroll
        for (int im = 0; im < 2; ++im)
#pragma unroll
            for (int ks = 0; ks < 2; ++ks)
                hah[im][ks] = frd(wb + (im * 16 + c) * SH + ks * 32 + 8 * q);

        // (3+4) GEMM-A: g = h @ W1 (m=i,n=d',k=d); write GB [d'][i] per jn
#pragma unroll
        for (int jn = 0; jn < 4; ++jn) {
            const unsigned short* wp = wsf + W1F + (l * 64 + jn * 16 + c) * 64;
            f16x8 b0 = gfrd(wp + 8 * q);
            f16x8 b1 = gfrd(wp + 32 + 8 * q);
            f32x4 g0 = {0.f, 0.f, 0.f, 0.f}, g1 = {0.f, 0.f, 0.f, 0.f};
            g0 = MFMA16(hah[0][0], b0, g0);
            g0 = MFMA16(hah[0][1], b1, g0);
            g1 = MFMA16(hah[1][0], b0, g1);
            g1 = MFMA16(hah[1][1], b1, g1);
            *(uint2*)(wb + (jn * 16 + c) * SG + 4 * q)      = pk4(g0[0], g0[1], g0[2], g0[3]);
            *(uint2*)(wb + (jn * 16 + c) * SG + 16 + 4 * q) = pk4(g1[0], g1[1], g1[2], g1[3]);
        }

        // (5) preload GEMM-B A-frags (g^T rows)
        f16x8 gah[4];
#pragma unroll
        for (int dm = 0; dm < 4; ++dm)
            gah[dm] = frd(wb + (dm * 16 + c) * SG + 8 * q);

        // (6+7) GEMM-B: t^T = g^T @ adjT (m=d',n=i,k=j); t -> HB with relu(+b1)
#pragma unroll
        for (int dm = 0; dm < 4; ++dm) {
            float4 b1v = *(const float4*)&prm[(l * 4 + 0) * 64 + dm * 16 + 4 * q];
            f32x4 t0 = {0.f, 0.f, 0.f, 0.f}, t1 = {0.f, 0.f, 0.f, 0.f};
            t0 = MFMA16(gah[dm], adjf[0], t0);
            t1 = MFMA16(gah[dm], adjf[1], t1);
            *(uint2*)(wb + c * SH + dm * 16 + 4 * q) =
                pk4(fmaxf(t0[0] + b1v.x, 0.f), fmaxf(t0[1] + b1v.y, 0.f),
                    fmaxf(t0[2] + b1v.z, 0.f), fmaxf(t0[3] + b1v.w, 0.f));
            *(uint2*)(wb + (16 + c) * SH + dm * 16 + 4 * q) =
                pk4(fmaxf(t1[0] + b1v.x, 0.f), fmaxf(t1[1] + b1v.y, 0.f),
                    fmaxf(t1[2] + b1v.z, 0.f), fmaxf(t1[3] + b1v.w, 0.f));
        }

        // (8) preload GEMM-C B-frags (t rows)
        f16x8 tbh[2][2];
#pragma unroll
        for (int in_ = 0; in_ < 2; ++in_)
#pragma unroll
            for (int ks = 0; ks < 2; ++ks)
                tbh[in_][ks] = frd(wb + (in_ * 16 + c) * SH + ks * 32 + 8 * q);

        // (9+10) GEMM-C': u^T = W2^T @ t^T (m=d,n=i,k=d'); LN; relu; residual
#pragma unroll
        for (int in_ = 0; in_ < 2; ++in_) {
            float v[16];
            float s1 = 0.f, s2 = 0.f;
#pragma unroll
            for (int dm = 0; dm < 4; ++dm) {
                const unsigned short* wp2 = wsf + W2F + (l * 64 + dm * 16 + c) * 64;
                f16x8 a0 = gfrd(wp2 + 8 * q);
                f16x8 a1 = gfrd(wp2 + 32 + 8 * q);
                f32x4 u = {0.f, 0.f, 0.f, 0.f};
                u = MFMA16(a0, tbh[in_][0], u);
                u = MFMA16(a1, tbh[in_][1], u);
                float4 b2v = *(const float4*)&prm[(l * 4 + 1) * 64 + dm * 16 + 4 * q];
                const float* bb = (const float*)&b2v;
#pragma unroll
                for (int r = 0; r < 4; ++r) {
                    float x = u[r] + bb[r];
                    v[dm * 4 + r] = x;
                    s1 += x;
                    s2 += x * x;
                }
            }
            s1 += __shfl_xor(s1, 16, 64); s1 += __shfl_xor(s1, 32, 64);
            s2 += __shfl_xor(s2, 16, 64); s2 += __shfl_xor(s2, 32, 64);
            float mean = s1 * (1.0f / HID);
            float var  = s2 * (1.0f / HID) - mean * mean;
            float rs   = rsqrtf(var + 1e-5f);
#pragma unroll
            for (int dm = 0; dm < 4; ++dm) {
                float4 gv4  = *(const float4*)&prm[(l * 4 + 2) * 64 + dm * 16 + 4 * q];
                float4 bev4 = *(const float4*)&prm[(l * 4 + 3) * 64 + dm * 16 + 4 * q];
                const float* gp = (const float*)&gv4;
                const float* bp = (const float*)&bev4;
                float y0 = fmaxf((v[dm * 4 + 0] - mean) * rs * gp[0] + bp[0], 0.f);
                float y1 = fmaxf((v[dm * 4 + 1] - mean) * rs * gp[1] + bp[1], 0.f);
                float y2 = fmaxf((v[dm * 4 + 2] - mean) * rs * gp[2] + bp[2], 0.f);
                float y3 = fmaxf((v[dm * 4 + 3] - mean) * rs * gp[3] + bp[3], 0.f);
                float2 h0 = upk2(hpk[in_ * 8 + dm * 2 + 0]);
                float2 h1 = upk2(hpk[in_ * 8 + dm * 2 + 1]);
                uint2 nu = pk4(h0.x + y0, h0.y + y1, h1.x + y2, h1.y + y3);
                hpk[in_ * 8 + dm * 2 + 0] = nu.x;
                hpk[in_ * 8 + dm * 2 + 1] = nu.y;
            }
        }
    }

    // ---- dump final h (fp16 [i][d]) into private buffer ----
#pragma unroll
    for (int in_ = 0; in_ < 2; ++in_)
#pragma unroll
        for (int dm = 0; dm < 4; ++dm)
            *(uint2*)(wb + (in_ * 16 + c) * SH + dm * 16 + 4 * q) =
                make_uint2(hpk[in_ * 8 + dm * 2], hpk[in_ * 8 + dm * 2 + 1]);
    __syncthreads();

    // ---- tail (wave 0): combine 6 perms, GEMM-D, colsum, set2, pooling ----
    if (w == 0) {
        f16x8 mah[2][2];
#pragma unroll
        for (int im = 0; im < 2; ++im) {
            float sc = ((im * 16 + c) < nn) ? (1.0f / PP) : 0.f;
#pragma unroll
            for (int ks = 0; ks < 2; ++ks) {
                int ro = (im * 16 + c) * SH + ks * 32 + 8 * q;
                float acc8[8];
#pragma unroll
                for (int j = 0; j < 8; ++j) acc8[j] = 0.f;
#pragma unroll
                for (int wv = 0; wv < 6; ++wv) {
                    f16x8 f = frd(WB + wv * WBU + ro);
#pragma unroll
                    for (int j = 0; j < 8; ++j) acc8[j] += (float)f[j];
                }
                f16x8 m;
#pragma unroll
                for (int j = 0; j < 8; ++j) m[j] = (_Float16)(acc8[j] * sc);
                mah[im][ks] = m;
            }
        }

        // GEMM-D: h1 = hm @ set1_W (m=i, n=dout)
        f32x4 hh[2][4];
#pragma unroll
        for (int im = 0; im < 2; ++im)
#pragma unroll
            for (int jn = 0; jn < 4; ++jn) hh[im][jn] = (f32x4){0.f, 0.f, 0.f, 0.f};
#pragma unroll
        for (int jn = 0; jn < 4; ++jn) {
            const unsigned short* sp = wsf + S1F + (jn * 16 + c) * 64;
            f16x8 b0 = gfrd(sp + 8 * q);
            f16x8 b1 = gfrd(sp + 32 + 8 * q);
#pragma unroll
            for (int im = 0; im < 2; ++im) {
                hh[im][jn] = MFMA16(mah[im][0], b0, hh[im][jn]);
                hh[im][jn] = MFMA16(mah[im][1], b1, hh[im][jn]);
            }
        }
        // colsum over all 32 rows (padded rows contribute relu(s1b), as ref)
#pragma unroll
        for (int jn = 0; jn < 4; ++jn) {
            float sb = s1bm[jn * 16 + c];
            float cs = 0.f;
#pragma unroll
            for (int im = 0; im < 2; ++im)
#pragma unroll
                for (int r = 0; r < 4; ++r)
                    cs += fmaxf(hh[im][jn][r] + sb, 0.f);
            cs += __shfl_xor(cs, 16, 64);
            cs += __shfl_xor(cs, 32, 64);
            if (q == 0) HSf[jn * 16 + c] = cs;
        }

        // h2 = relu(HS @ set2_W + s2b), lane = dout
        float acc = 0.f;
#pragma unroll
        for (int e4 = 0; e4 < 16; ++e4) {
            float4 wv = *(const float4*)&s2wt[lane * 64 + e4 * 4];
            float4 hv = *(const float4*)&HSf[e4 * 4];
            acc += hv.x * wv.x + hv.y * wv.y + hv.z * wv.z + hv.w * wv.w;
        }
        float h2 = fmaxf(acc + s2bm[lane], 0.f);

        // pooling fold: device-scope atomicMax (h2 >= 0: uint order == float order)
        atomicMax(&gmax[b * HID + lane], __float_as_uint(h2));
        __threadfence();
        unsigned old = 0;
        if (lane == 0) old = atomicAdd(&cnt[b], 1u);
        old = __shfl(old, 0, 64);
        if (old == NS - 1) {   // last block of this graph
            __threadfence();
            unsigned mbits = atomicOr(&gmax[b * HID + lane], 0u);
            float v = __uint_as_float(mbits) * outw[lane];
#pragma unroll
            for (int off = 32; off > 0; off >>= 1) v += __shfl_xor(v, off, 64);
            if (lane == 0) out[b] = v + outb[0];
        }
    }
}

extern "C" void kernel_launch(void* const* d_in, const int* in_sizes, int n_in,
                              void* d_out, int out_size, void* d_ws, size_t ws_size,
                              hipStream_t stream)
{
    const int*   xg       = (const int*)d_in[0];
    const float* subadj   = (const float*)d_in[1];
    const int*   subgs    = (const int*)d_in[2];
    const int*   num_node = (const int*)d_in[3];
    const float* idemb    = (const float*)d_in[5];
    const float* node_emb = (const float*)d_in[6];
    const float* w1       = (const float*)d_in[7];
    const float* b1       = (const float*)d_in[8];
    const float* w2       = (const float*)d_in[9];
    const float* b2       = (const float*)d_in[10];
    const float* g        = (const float*)d_in[11];
    const float* be       = (const float*)d_in[12];
    const float* s1w      = (const float*)d_in[13];
    const float* s1b      = (const float*)d_in[14];
    const float* s2w      = (const float*)d_in[15];
    const float* s2b      = (const float*)d_in[16];
    const float* outw     = (const float*)d_in[17];
    const float* outb     = (const float*)d_in[18];

    char* ws = (char*)d_ws;
    unsigned short* wsf = (unsigned short*)ws;
    const float* s2wt = (const float*)(ws + S2WT_BYTE);
    unsigned* gmax = (unsigned*)(ws + GMAX_BYTE);
    unsigned* cnt  = (unsigned*)(ws + CNT_BYTE);

    idmpnn_prep<<<177, 256, 0, stream>>>(w1, w2, s1w, s2w, ws);
    idmpnn_main<<<STOT, 384, 0, stream>>>(xg, subadj, subgs, num_node, idemb, node_emb,
                                          b1, b2, g, be, s1b, s2b, outw, outb,
                                          wsf, s2wt, gmax, cnt, (float*)d_out);
}

// Round 9
// 215.786 us; speedup vs baseline: 1.8328x; 1.1579x over previous
//
#include <hip/hip_runtime.h>
#include <math.h>

// IDMPNN fused forward — R8b: two subgraphs (same graph) per block, interleaved
// per wave for ILP-based latency hiding. (R8 failed to compile: cvt_pkrtz
// returns __fp16x2 not _Float16x2 — union type fixed, nothing else changed.)
// R7 showed ~1 resident block/CU no matter what -> serial ds/MFMA chain runs
// naked. Fix: each wave runs its perm for TWO independent chains (same
// adjacency/weights/embeddings since both subgraphs are in the same graph) —
// chain B fills chain A's stall slots. Also: v_cvt_pkrtz packing (1 op vs ~3)
// and v_pk_add_f16 residual update. Grid 1024 blocks x 384 thr (6 waves).

#define NBATCH 64
#define NM 32
#define NS 32
#define KSUB 3
#define HID 64
#define NLAYER 4
#define PP 6

// d_ws: fp16 weight planes (ushort offsets), then byte offsets
#define W1F 0            // [l][dout][din] 16384
#define W2F 16384
#define S1F 32768        // planes end at ushort 36864 = byte 73728
#define GMAX_BYTE 73728  // uint[64*64]
#define CNT_BYTE  90112  // uint[64]
#define S2WT_BYTE 90368  // float[64*64]

// LDS row strides (ushorts)
#define SH 68    // HB rows (32 x 64 fp16 + pad)
#define SG 36    // GB rows (64 x 32 fp16 + pad)
#define WBU 2304 // per-chain buffer ushorts (4608B): max(32*68, 64*36)

typedef _Float16 f16x8 __attribute__((ext_vector_type(8)));
typedef _Float16 f16x2 __attribute__((ext_vector_type(2)));
typedef __fp16 fp16x2 __attribute__((ext_vector_type(2)));   // cvt_pkrtz return type
typedef float f32x4 __attribute__((ext_vector_type(4)));

#define MFMA16(a, b, c) __builtin_amdgcn_mfma_f32_16x16x32_f16(a, b, c, 0, 0, 0)

__constant__ int c_perm[KSUB][PP] = {
    {0, 0, 1, 1, 2, 2},
    {1, 2, 0, 2, 0, 1},
    {2, 1, 2, 0, 1, 0}
};

__device__ __forceinline__ unsigned pk2rtz(float a, float b) {
    union { fp16x2 h; unsigned u; } x;
    x.h = __builtin_amdgcn_cvt_pkrtz(a, b);
    return x.u;
}
__device__ __forceinline__ uint2 pk4rtz(float a, float b, float c, float d) {
    return make_uint2(pk2rtz(a, b), pk2rtz(c, d));
}
__device__ __forceinline__ unsigned pkadd(unsigned hu, unsigned yu) {
    union { f16x2 h; unsigned u; } a, b;
    a.u = hu; b.u = yu;
    a.h = a.h + b.h;            // v_pk_add_f16
    return a.u;
}
__device__ __forceinline__ f16x8 frd(const unsigned short* p) {   // LDS, 8B-aligned
    union { struct { uint2 a, b; } u; f16x8 f; } x;
    x.u.a = *(const uint2*)p;
    x.u.b = *(const uint2*)(p + 4);
    return x.f;
}
__device__ __forceinline__ f16x8 gfrd(const unsigned short* p) {  // global, 16B-aligned
    union { uint4 u; f16x8 f; } x;
    x.u = *(const uint4*)p;
    return x.f;
}

// ---- prep: fp16 weight planes [l][dout][din] + s2w^T f32 + zero gmax/cnt ----
extern "C" __global__ void idmpnn_prep(const float* __restrict__ w1,
                                       const float* __restrict__ w2,
                                       const float* __restrict__ s1w,
                                       const float* __restrict__ s2w,
                                       char* __restrict__ ws)
{
    unsigned short* wsu = (unsigned short*)ws;
    int idx = blockIdx.x * 256 + threadIdx.x;
    float v; int dst;
    if (idx < 16384) {
        int l = idx >> 12, r = idx & 4095, dp = r >> 6, e = r & 63;
        v = w1[l * 4096 + e * 64 + dp];
        dst = W1F + idx;
    } else if (idx < 32768) {
        int k = idx - 16384;
        int l = k >> 12, r = k & 4095, dp = r >> 6, e = r & 63;
        v = w2[l * 4096 + e * 64 + dp];
        dst = W2F + k;
    } else if (idx < 36864) {
        int k = idx - 32768, dp = k >> 6, e = k & 63;
        v = s1w[e * 64 + dp];
        dst = S1F + k;
    } else if (idx < 40960) {
        int k = idx - 36864, dp = k >> 6, e = k & 63;
        ((float*)(ws + S2WT_BYTE))[k] = s2w[e * 64 + dp];
        return;
    } else if (idx < 45056) {
        ((unsigned*)(ws + GMAX_BYTE))[idx - 40960] = 0u;
        return;
    } else if (idx < 45120) {
        ((unsigned*)(ws + CNT_BYTE))[idx - 45056] = 0u;
        return;
    } else return;
    union { _Float16 h; unsigned short u; } cv;
    cv.h = (_Float16)v;                 // RNE (host-side once)
    wsu[dst] = cv.u;
}

extern "C" __global__ void __launch_bounds__(384, 2)
idmpnn_main(const int* __restrict__ xg, const float* __restrict__ subadj,
            const int* __restrict__ subgs, const int* __restrict__ num_node,
            const float* __restrict__ idemb, const float* __restrict__ node_emb,
            const float* __restrict__ b1g, const float* __restrict__ b2g,
            const float* __restrict__ lngm, const float* __restrict__ lnbm,
            const float* __restrict__ s1bm, const float* __restrict__ s2bm,
            const float* __restrict__ outw, const float* __restrict__ outb,
            const unsigned short* __restrict__ wsf, const float* __restrict__ s2wt,
            unsigned* __restrict__ gmax, unsigned* __restrict__ cnt,
            float* __restrict__ out)
{
    // 55296 + 768 + 4096 + 512 = 60672 B LDS
    __shared__ unsigned short WB[12 * WBU];  // [wave][chain] HB/GB views
    __shared__ float idS[KSUB * 64];
    __shared__ float prm[NLAYER * 4 * 64];   // b1,b2,g,be per layer
    __shared__ float HSf[2 * HID];

    const int s0 = blockIdx.x * 2;           // subgraphs s0, s0+1 (same graph)
    const int b = s0 >> 5;
    const int tid = threadIdx.x;
    const int w = tid / 64, lane = tid & 63; // w = perm id 0..5
    const int c = lane & 15, q = lane >> 4;

    for (int t = tid; t < NLAYER * 4 * 64; t += 384) {
        int l = t >> 8, r2 = t & 255, set = r2 >> 6, d = r2 & 63;
        const float* src = (set == 0) ? b1g : (set == 1) ? b2g : (set == 2) ? lngm : lnbm;
        prm[t] = src[l * HID + d];
    }
    if (tid < KSUB * 64) idS[tid] = idemb[tid];

    int nd[2][3];
#pragma unroll
    for (int ch = 0; ch < 2; ++ch)
#pragma unroll
        for (int k = 0; k < 3; ++k)
            nd[ch][k] = subgs[(s0 + ch) * KSUB + k];
    const int nn = num_node[b];
    const int zi0 = xg[b * NM + c];
    const int zi1 = xg[b * NM + 16 + c];

    // adjacency fp16 B-frags (shared by both chains — same graph)
    f16x8 adjf[2];
#pragma unroll
    for (int in_ = 0; in_ < 2; ++in_) {
        const float* ap = subadj + (size_t)b * NM * NM + (in_ * 16 + c) * NM + 8 * q;
        float4 f0 = *(const float4*)ap;
        float4 f1 = *(const float4*)(ap + 4);
        union { struct { uint2 a, b; } u; f16x8 f; } x;
        x.u.a = pk4rtz(f0.x, f0.y, f0.z, f0.w);
        x.u.b = pk4rtz(f1.x, f1.y, f1.z, f1.w);
        adjf[in_] = x.f;
    }

    __syncthreads();

    unsigned short* wbc[2] = { WB + (w * 2 + 0) * WBU, WB + (w * 2 + 1) * WBU };
    const int p = w;

    // h, packed 2xfp16: hpk[ch][in_*8+dm*2+g2] = (i=in_*16+c, d=dm*16+4q+2g2+{0,1})
    unsigned hpk[2][16];
#pragma unroll
    for (int in_ = 0; in_ < 2; ++in_) {
        int i = in_ * 16 + c;
        int z = in_ ? zi1 : zi0;
        int pid[2];
#pragma unroll
        for (int ch = 0; ch < 2; ++ch)
            pid[ch] = (i == nd[ch][0]) ? c_perm[0][p] : (i == nd[ch][1]) ? c_perm[1][p]
                      : (i == nd[ch][2]) ? c_perm[2][p] : -1;
#pragma unroll
        for (int dm = 0; dm < 4; ++dm) {
            float4 e4 = *(const float4*)(node_emb + (size_t)z * HID + dm * 16 + 4 * q);
#pragma unroll
            for (int ch = 0; ch < 2; ++ch) {
                float4 v = e4;
                if (pid[ch] >= 0) {
                    float4 f4 = *(const float4*)&idS[pid[ch] * 64 + dm * 16 + 4 * q];
                    v.x *= f4.x; v.y *= f4.y; v.z *= f4.z; v.w *= f4.w;
                }
                uint2 u = pk4rtz(v.x, v.y, v.z, v.w);
                hpk[ch][in_ * 8 + dm * 2 + 0] = u.x;
                hpk[ch][in_ * 8 + dm * 2 + 1] = u.y;
            }
        }
    }

#pragma unroll 1
    for (int l = 0; l < NLAYER; ++l) {
        // (1) h -> HB [i][d], both chains (reg moves, independent writes)
#pragma unroll
        for (int ch = 0; ch < 2; ++ch)
#pragma unroll
            for (int in_ = 0; in_ < 2; ++in_)
#pragma unroll
                for (int dm = 0; dm < 4; ++dm)
                    *(uint2*)(wbc[ch] + (in_ * 16 + c) * SH + dm * 16 + 4 * q) =
                        make_uint2(hpk[ch][in_ * 8 + dm * 2], hpk[ch][in_ * 8 + dm * 2 + 1]);

        // (2) GEMM-A A-frags, both chains
        f16x8 hah[2][2][2];
#pragma unroll
        for (int ch = 0; ch < 2; ++ch)
#pragma unroll
            for (int im = 0; im < 2; ++im)
#pragma unroll
                for (int ks = 0; ks < 2; ++ks)
                    hah[ch][im][ks] = frd(wbc[ch] + (im * 16 + c) * SH + ks * 32 + 8 * q);

        // (3+4) GEMM-A: g = h @ W1; write GB [d'][i] (weights shared)
#pragma unroll
        for (int jn = 0; jn < 4; ++jn) {
            const unsigned short* wp = wsf + W1F + (l * 64 + jn * 16 + c) * 64;
            f16x8 b0 = gfrd(wp + 8 * q);
            f16x8 b1 = gfrd(wp + 32 + 8 * q);
#pragma unroll
            for (int ch = 0; ch < 2; ++ch) {
                f32x4 g0 = {0.f, 0.f, 0.f, 0.f}, g1 = {0.f, 0.f, 0.f, 0.f};
                g0 = MFMA16(hah[ch][0][0], b0, g0);
                g0 = MFMA16(hah[ch][0][1], b1, g0);
                g1 = MFMA16(hah[ch][1][0], b0, g1);
                g1 = MFMA16(hah[ch][1][1], b1, g1);
                *(uint2*)(wbc[ch] + (jn * 16 + c) * SG + 4 * q)      = pk4rtz(g0[0], g0[1], g0[2], g0[3]);
                *(uint2*)(wbc[ch] + (jn * 16 + c) * SG + 16 + 4 * q) = pk4rtz(g1[0], g1[1], g1[2], g1[3]);
            }
        }

        // (5) GEMM-B A-frags
        f16x8 gah[2][4];
#pragma unroll
        for (int ch = 0; ch < 2; ++ch)
#pragma unroll
            for (int dm = 0; dm < 4; ++dm)
                gah[ch][dm] = frd(wbc[ch] + (dm * 16 + c) * SG + 8 * q);

        // (6+7) GEMM-B: t^T = g^T @ adjT; t -> HB with relu(+b1)
#pragma unroll
        for (int dm = 0; dm < 4; ++dm) {
            float4 b1v = *(const float4*)&prm[(l * 4 + 0) * 64 + dm * 16 + 4 * q];
#pragma unroll
            for (int ch = 0; ch < 2; ++ch) {
                f32x4 t0 = {0.f, 0.f, 0.f, 0.f}, t1 = {0.f, 0.f, 0.f, 0.f};
                t0 = MFMA16(gah[ch][dm], adjf[0], t0);
                t1 = MFMA16(gah[ch][dm], adjf[1], t1);
                *(uint2*)(wbc[ch] + c * SH + dm * 16 + 4 * q) =
                    pk4rtz(fmaxf(t0[0] + b1v.x, 0.f), fmaxf(t0[1] + b1v.y, 0.f),
                           fmaxf(t0[2] + b1v.z, 0.f), fmaxf(t0[3] + b1v.w, 0.f));
                *(uint2*)(wbc[ch] + (16 + c) * SH + dm * 16 + 4 * q) =
                    pk4rtz(fmaxf(t1[0] + b1v.x, 0.f), fmaxf(t1[1] + b1v.y, 0.f),
                           fmaxf(t1[2] + b1v.z, 0.f), fmaxf(t1[3] + b1v.w, 0.f));
            }
        }

        // (8) GEMM-C B-frags
        f16x8 tbh[2][2][2];
#pragma unroll
        for (int ch = 0; ch < 2; ++ch)
#pragma unroll
            for (int in_ = 0; in_ < 2; ++in_)
#pragma unroll
                for (int ks = 0; ks < 2; ++ks)
                    tbh[ch][in_][ks] = frd(wbc[ch] + (in_ * 16 + c) * SH + ks * 32 + 8 * q);

        // (9+10) GEMM-C': u^T = W2^T @ t^T; LN; relu; residual (pk add)
#pragma unroll
        for (int in_ = 0; in_ < 2; ++in_) {
            float v[2][16];
            float s1[2] = {0.f, 0.f}, s2[2] = {0.f, 0.f};
#pragma unroll
            for (int dm = 0; dm < 4; ++dm) {
                const unsigned short* wp2 = wsf + W2F + (l * 64 + dm * 16 + c) * 64;
                f16x8 a0 = gfrd(wp2 + 8 * q);
                f16x8 a1 = gfrd(wp2 + 32 + 8 * q);
                float4 b2v = *(const float4*)&prm[(l * 4 + 1) * 64 + dm * 16 + 4 * q];
                const float* bb = (const float*)&b2v;
#pragma unroll
                for (int ch = 0; ch < 2; ++ch) {
                    f32x4 u = {0.f, 0.f, 0.f, 0.f};
                    u = MFMA16(a0, tbh[ch][in_][0], u);
                    u = MFMA16(a1, tbh[ch][in_][1], u);
#pragma unroll
                    for (int r = 0; r < 4; ++r) {
                        float x = u[r] + bb[r];
                        v[ch][dm * 4 + r] = x;
                        s1[ch] += x;
                        s2[ch] += x * x;
                    }
                }
            }
#pragma unroll
            for (int ch = 0; ch < 2; ++ch) {
                float a1 = s1[ch], a2 = s2[ch];
                a1 += __shfl_xor(a1, 16, 64); a1 += __shfl_xor(a1, 32, 64);
                a2 += __shfl_xor(a2, 16, 64); a2 += __shfl_xor(a2, 32, 64);
                float mean = a1 * (1.0f / HID);
                float var  = a2 * (1.0f / HID) - mean * mean;
                float rs   = rsqrtf(var + 1e-5f);
#pragma unroll
                for (int dm = 0; dm < 4; ++dm) {
                    float4 gv4  = *(const float4*)&prm[(l * 4 + 2) * 64 + dm * 16 + 4 * q];
                    float4 bev4 = *(const float4*)&prm[(l * 4 + 3) * 64 + dm * 16 + 4 * q];
                    const float* gp = (const float*)&gv4;
                    const float* bp = (const float*)&bev4;
                    float y0 = fmaxf((v[ch][dm * 4 + 0] - mean) * rs * gp[0] + bp[0], 0.f);
                    float y1 = fmaxf((v[ch][dm * 4 + 1] - mean) * rs * gp[1] + bp[1], 0.f);
                    float y2 = fmaxf((v[ch][dm * 4 + 2] - mean) * rs * gp[2] + bp[2], 0.f);
                    float y3 = fmaxf((v[ch][dm * 4 + 3] - mean) * rs * gp[3] + bp[3], 0.f);
                    int i0 = in_ * 8 + dm * 2;
                    hpk[ch][i0 + 0] = pkadd(hpk[ch][i0 + 0], pk2rtz(y0, y1));
                    hpk[ch][i0 + 1] = pkadd(hpk[ch][i0 + 1], pk2rtz(y2, y3));
                }
            }
        }
    }

    // ---- dump final h (fp16 [i][d]) into private buffers ----
#pragma unroll
    for (int ch = 0; ch < 2; ++ch)
#pragma unroll
        for (int in_ = 0; in_ < 2; ++in_)
#pragma unroll
            for (int dm = 0; dm < 4; ++dm)
                *(uint2*)(wbc[ch] + (in_ * 16 + c) * SH + dm * 16 + 4 * q) =
                    make_uint2(hpk[ch][in_ * 8 + dm * 2], hpk[ch][in_ * 8 + dm * 2 + 1]);
    __syncthreads();

    // ---- tail: wave 0 -> subgraph s0, wave 1 -> subgraph s0+1 ----
    if (w < 2) {
        // combine 6 perms of chain w
        f16x8 mah[2][2];
#pragma unroll
        for (int im = 0; im < 2; ++im) {
            float sc = ((im * 16 + c) < nn) ? (1.0f / PP) : 0.f;
#pragma unroll
            for (int ks = 0; ks < 2; ++ks) {
                int ro = (im * 16 + c) * SH + ks * 32 + 8 * q;
                float acc8[8];
#pragma unroll
                for (int j = 0; j < 8; ++j) acc8[j] = 0.f;
#pragma unroll
                for (int wv = 0; wv < 6; ++wv) {
                    f16x8 f = frd(WB + (wv * 2 + w) * WBU + ro);
#pragma unroll
                    for (int j = 0; j < 8; ++j) acc8[j] += (float)f[j];
                }
                f16x8 m;
#pragma unroll
                for (int j = 0; j < 8; ++j) m[j] = (_Float16)(acc8[j] * sc);
                mah[im][ks] = m;
            }
        }

        // GEMM-D: h1 = hm @ set1_W (m=i, n=dout)
        f32x4 hh[2][4];
#pragma unroll
        for (int im = 0; im < 2; ++im)
#pragma unroll
            for (int jn = 0; jn < 4; ++jn) hh[im][jn] = (f32x4){0.f, 0.f, 0.f, 0.f};
#pragma unroll
        for (int jn = 0; jn < 4; ++jn) {
            const unsigned short* sp = wsf + S1F + (jn * 16 + c) * 64;
            f16x8 b0 = gfrd(sp + 8 * q);
            f16x8 b1 = gfrd(sp + 32 + 8 * q);
#pragma unroll
            for (int im = 0; im < 2; ++im) {
                hh[im][jn] = MFMA16(mah[im][0], b0, hh[im][jn]);
                hh[im][jn] = MFMA16(mah[im][1], b1, hh[im][jn]);
            }
        }
        // colsum over all 32 rows (padded rows contribute relu(s1b), as ref)
#pragma unroll
        for (int jn = 0; jn < 4; ++jn) {
            float sb = s1bm[jn * 16 + c];
            float cs = 0.f;
#pragma unroll
            for (int im = 0; im < 2; ++im)
#pragma unroll
                for (int r = 0; r < 4; ++r)
                    cs += fmaxf(hh[im][jn][r] + sb, 0.f);
            cs += __shfl_xor(cs, 16, 64);
            cs += __shfl_xor(cs, 32, 64);
            if (q == 0) HSf[w * HID + jn * 16 + c] = cs;
        }

        // h2 = relu(HS @ set2_W + s2b), lane = dout
        float acc = 0.f;
#pragma unroll
        for (int e4 = 0; e4 < 16; ++e4) {
            float4 wv = *(const float4*)&s2wt[lane * 64 + e4 * 4];
            float4 hv = *(const float4*)&HSf[w * HID + e4 * 4];
            acc += hv.x * wv.x + hv.y * wv.y + hv.z * wv.z + hv.w * wv.w;
        }
        float h2 = fmaxf(acc + s2bm[lane], 0.f);

        // pooling fold: device-scope atomicMax (h2 >= 0: uint order == float order)
        atomicMax(&gmax[b * HID + lane], __float_as_uint(h2));
        __threadfence();
        unsigned old = 0;
        if (lane == 0) old = atomicAdd(&cnt[b], 1u);
        old = __shfl(old, 0, 64);
        if (old == NS - 1) {   // last of the 32 subgraph-writers of this graph
            __threadfence();
            unsigned mbits = atomicOr(&gmax[b * HID + lane], 0u);
            float v = __uint_as_float(mbits) * outw[lane];
#pragma unroll
            for (int off = 32; off > 0; off >>= 1) v += __shfl_xor(v, off, 64);
            if (lane == 0) out[b] = v + outb[0];
        }
    }
}

extern "C" void kernel_launch(void* const* d_in, const int* in_sizes, int n_in,
                              void* d_out, int out_size, void* d_ws, size_t ws_size,
                              hipStream_t stream)
{
    const int*   xg       = (const int*)d_in[0];
    const float* subadj   = (const float*)d_in[1];
    const int*   subgs    = (const int*)d_in[2];
    const int*   num_node = (const int*)d_in[3];
    const float* idemb    = (const float*)d_in[5];
    const float* node_emb = (const float*)d_in[6];
    const float* w1       = (const float*)d_in[7];
    const float* b1       = (const float*)d_in[8];
    const float* w2       = (const float*)d_in[9];
    const float* b2       = (const float*)d_in[10];
    const float* g        = (const float*)d_in[11];
    const float* be       = (const float*)d_in[12];
    const float* s1w      = (const float*)d_in[13];
    const float* s1b      = (const float*)d_in[14];
    const float* s2w      = (const float*)d_in[15];
    const float* s2b      = (const float*)d_in[16];
    const float* outw     = (const float*)d_in[17];
    const float* outb     = (const float*)d_in[18];

    char* ws = (char*)d_ws;
    unsigned short* wsf = (unsigned short*)ws;
    const float* s2wt = (const float*)(ws + S2WT_BYTE);
    unsigned* gmax = (unsigned*)(ws + GMAX_BYTE);
    unsigned* cnt  = (unsigned*)(ws + CNT_BYTE);

    idmpnn_prep<<<177, 256, 0, stream>>>(w1, w2, s1w, s2w, ws);
    idmpnn_main<<<NBATCH * NS / 2, 384, 0, stream>>>(xg, subadj, subgs, num_node,
                                          idemb, node_emb,
                                          b1, b2, g, be, s1b, s2b, outw, outb,
                                          wsf, s2wt, gmax, cnt, (float*)d_out);
}